// Round 1
// baseline (2997.541 us; speedup 1.0000x reference)
//
#include <hip/hip_runtime.h>
#include <math.h>

#define NH 12
#define DM 768
#define DH 64
#define SS 1024
#define NB 4

// ws layout (floats):
//   Q   : [8 bp][12 n][1024 s][64 h]   6291456
//   Kt  : [8 bp][12 n][64 h][1024 s]   6291456
//   V   : [8 bp][12 n][1024 s][64 h]   6291456
//   Z   : [8 bp][12 n][1024 s][64 h]   6291456
//   sum1: [4 b][1024 q][768 d] (incl b_O) 3145728
#define WS_Q 0
#define WS_KT 6291456
#define WS_V 12582912
#define WS_Z 18874368
#define WS_SUM1 25165824

// ---------------- Kernel A: QKV projection GEMM ----------------
// C[m=(bp,s), col=(t,n,h)] = x[m,:] @ W_t[n][:, h]  (+bias; Q scaled by 1/8)
__global__ __launch_bounds__(256) void qkv_gemm_k(
    const float* __restrict__ x0, const float* __restrict__ x1,
    const float* __restrict__ WQ, const float* __restrict__ bQ,
    const float* __restrict__ WK, const float* __restrict__ bK,
    const float* __restrict__ WV, const float* __restrict__ bV,
    float* __restrict__ Q, float* __restrict__ Kt, float* __restrict__ V)
{
    __shared__ float As[16][68];
    __shared__ float Bs[16][68];
    const int tid = threadIdx.x;
    const int jt = blockIdx.x;   // 0..35 : t*12+n
    const int mt = blockIdx.y;   // 0..127
    const int t = jt / NH, n = jt % NH;
    const float* W    = (t == 0) ? WQ : (t == 1) ? WK : WV;
    const float* bias = (t == 0) ? bQ : (t == 1) ? bK : bV;

    const int mbase = mt * 64;
    const int bp = mbase >> 10;      // uniform for the whole tile
    const int b  = bp >> 1;
    const int p  = bp & 1;
    const int sbase = mbase & 1023;

    // A-tile load assignment: 64 rows x 16 k, float4 per thread
    const int mi = tid >> 2;            // 0..63
    const int k4 = (tid & 3) * 4;       // 0,4,8,12
    const float* arow = ((p == 0) ? x0 : x1)
        + (size_t)b * (SS * DM) + (size_t)(sbase + mi) * DM + k4;

    // B-tile load assignment: 16 k x 64 cols (h), float4 per thread
    const int bkk = tid >> 4;           // 0..15
    const int j4  = (tid & 15) * 4;     // 0..60
    const float* brow = W + (size_t)n * (DM * DH) + (size_t)bkk * DH + j4;

    const int tx = tid & 15, ty = tid >> 4;
    float acc[4][4] = {};

    for (int kt = 0; kt < 48; kt++) {
        float4 av = *(const float4*)(arow + kt * 16);
        float4 bv = *(const float4*)(brow + (size_t)kt * 16 * DH);
        __syncthreads();
        As[k4 + 0][mi] = av.x; As[k4 + 1][mi] = av.y;
        As[k4 + 2][mi] = av.z; As[k4 + 3][mi] = av.w;
        *(float4*)&Bs[bkk][j4] = bv;
        __syncthreads();
#pragma unroll
        for (int kk = 0; kk < 16; kk++) {
            float4 a4 = *(const float4*)&As[kk][ty * 4];
            float4 b4 = *(const float4*)&Bs[kk][tx * 4];
            float aa[4] = {a4.x, a4.y, a4.z, a4.w};
            float bb[4] = {b4.x, b4.y, b4.z, b4.w};
#pragma unroll
            for (int i = 0; i < 4; i++)
#pragma unroll
                for (int j = 0; j < 4; j++)
                    acc[i][j] += aa[i] * bb[j];
        }
    }

    const size_t headbase = ((size_t)bp * NH + n) * (SS * DH);
#pragma unroll
    for (int i = 0; i < 4; i++) {
        const int s = sbase + ty * 4 + i;
#pragma unroll
        for (int j = 0; j < 4; j++) {
            const int h = tx * 4 + j;
            const float v = acc[i][j] + bias[n * DH + h];
            if (t == 0)      Q [headbase + (size_t)s * DH + h] = v * 0.125f;
            else if (t == 1) Kt[headbase + (size_t)h * SS + s] = v;
            else             V [headbase + (size_t)s * DH + h] = v;
        }
    }
}

// ---------------- Kernel B: causal attention (softmax(QK^T)V) ----------------
// 1 wave per query row; 4 rows per block. Kt layout gives coalesced key loads.
__global__ __launch_bounds__(256) void attn_k(
    const float* __restrict__ Q, const float* __restrict__ Kt,
    const float* __restrict__ V, float* __restrict__ Z)
{
    __shared__ float P[4][SS];
    const int head = blockIdx.x;           // bp*NH + n
    const int wave = threadIdx.x >> 6;
    const int lane = threadIdx.x & 63;
    const int q = blockIdx.y * 4 + wave;
    const size_t hb = (size_t)head * (SS * DH);

    // whole Q row in registers (wave-uniform addresses)
    float qv[64];
    const float4* qrow = (const float4*)(Q + hb + (size_t)q * DH);
#pragma unroll
    for (int i = 0; i < 16; i++) {
        float4 v4 = qrow[i];
        qv[4*i] = v4.x; qv[4*i+1] = v4.y; qv[4*i+2] = v4.z; qv[4*i+3] = v4.w;
    }

    const float* Kh = Kt + hb;
    const int ng = (q >> 6) + 1;           // 64-key groups covering 0..q
    float mloc = -INFINITY;
    for (int g = 0; g < ng; g++) {
        const int j = g * 64 + lane;
        float s = -INFINITY;
        if (j <= q) {
            float acc = 0.f;
#pragma unroll
            for (int h = 0; h < 64; h++) acc += qv[h] * Kh[h * SS + j];
            s = acc;
        }
        P[wave][g * 64 + lane] = s;
        mloc = fmaxf(mloc, s);
    }
#pragma unroll
    for (int off = 32; off > 0; off >>= 1)
        mloc = fmaxf(mloc, __shfl_xor(mloc, off, 64));

    float ssum = 0.f;
    for (int g = 0; g < ng; g++) {
        const float sv = P[wave][g * 64 + lane];
        const float e = __expf(sv - mloc);  // -inf -> 0
        P[wave][g * 64 + lane] = e;
        ssum += e;
    }
#pragma unroll
    for (int off = 32; off > 0; off >>= 1)
        ssum += __shfl_xor(ssum, off, 64);
    const float inv = 1.f / ssum;

    float z = 0.f;
    const float* Vh = V + hb + lane;
    const int jmax = ng * 64;               // padded with zeros past q
    for (int j4 = 0; j4 < jmax; j4 += 4) {
        const float4 p4 = *(const float4*)&P[wave][j4];
        const float* vb = Vh + (size_t)j4 * DH;
        z += p4.x * vb[0] + p4.y * vb[DH] + p4.z * vb[2 * DH] + p4.w * vb[3 * DH];
    }
    Z[hb + (size_t)q * DH + lane] = z * inv;
}

// ---------------- Kernel C: sum over heads GEMM ----------------
// out[b,pp] = Zfull_bp (1024 x 768) @ WO_flat (768 x 768) + b_O;  pp==1 -> also sum1
__global__ __launch_bounds__(256) void sum_gemm_k(
    const float* __restrict__ Z, const float* __restrict__ WO,
    const float* __restrict__ bO, float* __restrict__ out, float* __restrict__ sum1)
{
    __shared__ float As[16][68];
    __shared__ float Bs[16][68];
    const int tid = threadIdx.x;
    const int nt = blockIdx.x;    // 0..11
    const int mt = blockIdx.y;    // 0..15
    const int bp = blockIdx.z;    // 0..7

    const int mi = tid >> 2;
    const int k4 = (tid & 3) * 4;
    const float* zrow = Z + (size_t)bp * (NH * SS * DH) + (size_t)(mt * 64 + mi) * DH;

    const int bkk = tid >> 4;
    const int j4  = (tid & 15) * 4;
    const float* brow = WO + (size_t)bkk * DM + nt * 64 + j4;

    const int tx = tid & 15, ty = tid >> 4;
    float acc[4][4] = {};

    for (int kt = 0; kt < 48; kt++) {
        const int kk = kt * 16 + k4;        // n = kk>>6, h = kk&63 (stays in-block)
        float4 av = *(const float4*)(zrow + (size_t)(kk >> 6) * (SS * DH) + (kk & 63));
        float4 bv = *(const float4*)(brow + (size_t)kt * 16 * DM);
        __syncthreads();
        As[k4 + 0][mi] = av.x; As[k4 + 1][mi] = av.y;
        As[k4 + 2][mi] = av.z; As[k4 + 3][mi] = av.w;
        *(float4*)&Bs[bkk][j4] = bv;
        __syncthreads();
#pragma unroll
        for (int kk2 = 0; kk2 < 16; kk2++) {
            float4 a4 = *(const float4*)&As[kk2][ty * 4];
            float4 b4 = *(const float4*)&Bs[kk2][tx * 4];
            float aa[4] = {a4.x, a4.y, a4.z, a4.w};
            float bb[4] = {b4.x, b4.y, b4.z, b4.w};
#pragma unroll
            for (int i = 0; i < 4; i++)
#pragma unroll
                for (int j = 0; j < 4; j++)
                    acc[i][j] += aa[i] * bb[j];
        }
    }

    const int b_ = bp >> 1, pp = bp & 1;
#pragma unroll
    for (int i = 0; i < 4; i++) {
        const int q = mt * 64 + ty * 4 + i;
#pragma unroll
        for (int j = 0; j < 4; j++) {
            const int d = nt * 64 + tx * 4 + j;
            const float v = acc[i][j] + bO[d];
            out[(((size_t)b_ * 14 + pp) * SS + q) * DM + d] = v;
            if (pp) sum1[((size_t)b_ * SS + q) * DM + d] = v;  // includes b_O
        }
    }
}

// ---------------- Kernel D: per-head diff GEMM + combine ----------------
// out[b,2+k] = (Z0_k - Z1_k)(1024x64) @ WO[k](64x768) + sum1
__global__ __launch_bounds__(256) void headdiff_k(
    const float* __restrict__ Z, const float* __restrict__ WO,
    const float* __restrict__ sum1, float* __restrict__ out)
{
    __shared__ float As[16][68];
    __shared__ float Bs[16][68];
    const int tid = threadIdx.x;
    const int nt = blockIdx.x;    // 0..11
    const int mt = blockIdx.y;    // 0..15
    const int bk = blockIdx.z;    // 0..47
    const int b_ = bk / NH, k = bk % NH;

    const size_t z0 = ((size_t)(b_ * 2)     * NH + k) * (SS * DH);
    const size_t z1 = ((size_t)(b_ * 2 + 1) * NH + k) * (SS * DH);

    const int mi = tid >> 2;
    const int k4 = (tid & 3) * 4;
    const float* zr0 = Z + z0 + (size_t)(mt * 64 + mi) * DH;
    const float* zr1 = Z + z1 + (size_t)(mt * 64 + mi) * DH;

    const int bkk = tid >> 4;
    const int j4  = (tid & 15) * 4;
    const float* brow = WO + (size_t)k * (DH * DM) + (size_t)bkk * DM + nt * 64 + j4;

    const int tx = tid & 15, ty = tid >> 4;
    float acc[4][4] = {};

    for (int kt = 0; kt < 4; kt++) {
        float4 a0 = *(const float4*)(zr0 + kt * 16 + k4);
        float4 a1 = *(const float4*)(zr1 + kt * 16 + k4);
        float4 bv = *(const float4*)(brow + (size_t)kt * 16 * DM);
        __syncthreads();
        As[k4 + 0][mi] = a0.x - a1.x; As[k4 + 1][mi] = a0.y - a1.y;
        As[k4 + 2][mi] = a0.z - a1.z; As[k4 + 3][mi] = a0.w - a1.w;
        *(float4*)&Bs[bkk][j4] = bv;
        __syncthreads();
#pragma unroll
        for (int kk2 = 0; kk2 < 16; kk2++) {
            float4 a4 = *(const float4*)&As[kk2][ty * 4];
            float4 b4 = *(const float4*)&Bs[kk2][tx * 4];
            float aa[4] = {a4.x, a4.y, a4.z, a4.w};
            float bb[4] = {b4.x, b4.y, b4.z, b4.w};
#pragma unroll
            for (int i = 0; i < 4; i++)
#pragma unroll
                for (int j = 0; j < 4; j++)
                    acc[i][j] += aa[i] * bb[j];
        }
    }

#pragma unroll
    for (int i = 0; i < 4; i++) {
        const int q = mt * 64 + ty * 4 + i;
#pragma unroll
        for (int j = 0; j < 4; j++) {
            const int d = nt * 64 + tx * 4 + j;
            out[(((size_t)b_ * 14 + 2 + k) * SS + q) * DM + d] =
                acc[i][j] + sum1[((size_t)b_ * SS + q) * DM + d];
        }
    }
}

extern "C" void kernel_launch(void* const* d_in, const int* in_sizes, int n_in,
                              void* d_out, int out_size, void* d_ws, size_t ws_size,
                              hipStream_t stream)
{
    const float* x0 = (const float*)d_in[0];  // normalized_resid_pre (4,1,1024,768)
    const float* x1 = (const float*)d_in[1];  // alt_normalized_resid_pre (4,1024,768)
    const float* WQ = (const float*)d_in[2];
    const float* bQ = (const float*)d_in[3];
    const float* WK = (const float*)d_in[4];
    const float* bK = (const float*)d_in[5];
    const float* WV = (const float*)d_in[6];
    const float* bV = (const float*)d_in[7];
    const float* WO = (const float*)d_in[8];
    const float* bO = (const float*)d_in[9];
    float* out = (float*)d_out;

    float* ws = (float*)d_ws;
    float* Q    = ws + WS_Q;
    float* Kt   = ws + WS_KT;
    float* V    = ws + WS_V;
    float* Z    = ws + WS_Z;
    float* sum1 = ws + WS_SUM1;

    qkv_gemm_k<<<dim3(36, 128), 256, 0, stream>>>(x0, x1, WQ, bQ, WK, bK, WV, bV, Q, Kt, V);
    attn_k<<<dim3(96, 256), 256, 0, stream>>>(Q, Kt, V, Z);
    sum_gemm_k<<<dim3(12, 16, 8), 256, 0, stream>>>(Z, WO, bO, out, sum1);
    headdiff_k<<<dim3(12, 16, 48), 256, 0, stream>>>(Z, WO, sum1, out);
}

// Round 2
// 875.157 us; speedup vs baseline: 3.4251x; 3.4251x over previous
//
#include <hip/hip_runtime.h>
#include <math.h>

#define NH 12
#define DM 768
#define DH 64
#define SS 1024

typedef __attribute__((ext_vector_type(8))) short short8;
typedef __attribute__((ext_vector_type(4))) float floatx4;

__device__ __forceinline__ ushort f2bf(float f) {
    union { float f; unsigned u; } v; v.f = f;
    unsigned r = v.u + 0x7fffu + ((v.u >> 16) & 1u);
    return (ushort)(r >> 16);
}

// ws layout (float units):
//   Z    : fp32 [8 bp][12 n][1024 s][64 h]          @ 0        (6291456 floats)
//   sum1 : fp32 [4 b][1024 q][768 d] (incl b_O)     @ 6291456  (3145728 floats)
//   Qb   : bf16 [8 bp][12 n][1024 s][64 h] (x0.125) @ 9437184  (6291456 ushorts)
//   Kb   : bf16 [8 bp][12 n][1024 s][64 h]          (+6291456 ushorts)
//   Vtb  : bf16 [8 bp][12 n][64 h][1024 s]          (+6291456 ushorts)

// ---------------- Kernel A: QKV projection GEMM (fp32 compute, bf16 out) ----------------
__global__ __launch_bounds__(256) void qkv_gemm_k(
    const float* __restrict__ x0, const float* __restrict__ x1,
    const float* __restrict__ WQ, const float* __restrict__ bQ,
    const float* __restrict__ WK, const float* __restrict__ bK,
    const float* __restrict__ WV, const float* __restrict__ bV,
    ushort* __restrict__ Qb, ushort* __restrict__ Kb, ushort* __restrict__ Vtb)
{
    __shared__ float As[16][68];
    __shared__ float Bs[16][68];
    const int tid = threadIdx.x;
    const int jt = blockIdx.x;   // 0..35 : t*12+n
    const int mt = blockIdx.y;   // 0..127
    const int t = jt / NH, n = jt % NH;
    const float* W    = (t == 0) ? WQ : (t == 1) ? WK : WV;
    const float* bias = (t == 0) ? bQ : (t == 1) ? bK : bV;

    const int mbase = mt * 64;
    const int bp = mbase >> 10;
    const int b  = bp >> 1;
    const int p  = bp & 1;
    const int sbase = mbase & 1023;

    const int mi = tid >> 2;            // 0..63
    const int k4 = (tid & 3) * 4;       // 0,4,8,12
    const float* arow = ((p == 0) ? x0 : x1)
        + (size_t)b * (SS * DM) + (size_t)(sbase + mi) * DM + k4;

    const int bkk = tid >> 4;           // 0..15
    const int j4  = (tid & 15) * 4;     // 0..60
    const float* brow = W + (size_t)n * (DM * DH) + (size_t)bkk * DH + j4;

    const int tx = tid & 15, ty = tid >> 4;
    float acc[4][4] = {};

    for (int kt = 0; kt < 48; kt++) {
        float4 av = *(const float4*)(arow + kt * 16);
        float4 bv = *(const float4*)(brow + (size_t)kt * 16 * DH);
        __syncthreads();
        As[k4 + 0][mi] = av.x; As[k4 + 1][mi] = av.y;
        As[k4 + 2][mi] = av.z; As[k4 + 3][mi] = av.w;
        *(float4*)&Bs[bkk][j4] = bv;
        __syncthreads();
#pragma unroll
        for (int kk = 0; kk < 16; kk++) {
            float4 a4 = *(const float4*)&As[kk][ty * 4];
            float4 b4 = *(const float4*)&Bs[kk][tx * 4];
            float aa[4] = {a4.x, a4.y, a4.z, a4.w};
            float bb[4] = {b4.x, b4.y, b4.z, b4.w};
#pragma unroll
            for (int i = 0; i < 4; i++)
#pragma unroll
                for (int j = 0; j < 4; j++)
                    acc[i][j] += aa[i] * bb[j];
        }
    }

    const size_t headbase = ((size_t)bp * NH + n) * (SS * DH);
#pragma unroll
    for (int i = 0; i < 4; i++) {
        const int s = sbase + ty * 4 + i;
#pragma unroll
        for (int j = 0; j < 4; j++) {
            const int h = tx * 4 + j;
            const float v = acc[i][j] + bias[n * DH + h];
            if (t == 0)      Qb [headbase + (size_t)s * DH + h] = f2bf(v * 0.125f);
            else if (t == 1) Kb [headbase + (size_t)s * DH + h] = f2bf(v);
            else             Vtb[headbase + (size_t)h * SS + s] = f2bf(v);
        }
    }
}

// ---------------- Kernel B: MFMA flash attention ----------------
// grid (96 heads, 16 q-blocks of 64); 4 waves/block, each wave owns a 16-row Q strip.
// A-frag: [m=lane&15][k=quad*8+j]; B-frag: [k=quad*8+j][n=lane&15]; C: col=lane&15,row=quad*4+reg.
__global__ __launch_bounds__(256) void attn_mfma_k(
    const ushort* __restrict__ Qb, const ushort* __restrict__ Kb,
    const ushort* __restrict__ Vtb, float* __restrict__ Z)
{
    __shared__ __align__(16) ushort P_lds[4][16][72];   // +8 pad: 2-way banks (free)
    const int head = blockIdx.x;
    const int wave = threadIdx.x >> 6;
    const int lane = threadIdx.x & 63;
    const int quad = lane >> 4;
    const int l16  = lane & 15;
    const int qbase = blockIdx.y * 64 + wave * 16;

    const size_t hb = (size_t)head * (SS * DH);
    const ushort* Qh = Qb + hb;
    const ushort* Kh = Kb + hb;
    const ushort* Vh = Vtb + hb;    // [h][s]

    // Q strip A-frags (K-dim 64 split over 2 MFMAs)
    short8 a_q0 = *(const short8*)(Qh + (size_t)(qbase + l16) * DH + quad * 8);
    short8 a_q1 = *(const short8*)(Qh + (size_t)(qbase + l16) * DH + 32 + quad * 8);

    floatx4 o[4];                    // 4 h-groups of 16
    float m_run[4], l_run[4];
#pragma unroll
    for (int r = 0; r < 4; r++) {
        o[r] = (floatx4){0.f, 0.f, 0.f, 0.f};
        m_run[r] = -1e30f; l_run[r] = 0.f;
    }

    const int kb_last = (qbase + 15) >> 6;
    for (int kb = 0; kb <= kb_last; kb++) {
        // ---- S = Q K^T (16 x 64) ----
        floatx4 c[4];
#pragma unroll
        for (int kg = 0; kg < 4; kg++) {
            const ushort* krow = Kh + (size_t)(kb * 64 + kg * 16 + l16) * DH + quad * 8;
            short8 b0 = *(const short8*)(krow);
            short8 b1 = *(const short8*)(krow + 32);
            floatx4 cc = (floatx4){0.f, 0.f, 0.f, 0.f};
            cc = __builtin_amdgcn_mfma_f32_16x16x32_bf16(a_q0, b0, cc, 0, 0, 0);
            cc = __builtin_amdgcn_mfma_f32_16x16x32_bf16(a_q1, b1, cc, 0, 0, 0);
            c[kg] = cc;
        }
        // ---- causal mask (only the diagonal tile) ----
        if (kb == kb_last) {
#pragma unroll
            for (int kg = 0; kg < 4; kg++) {
                const int key = kb * 64 + kg * 16 + l16;
#pragma unroll
                for (int r = 0; r < 4; r++) {
                    const int q = qbase + quad * 4 + r;
                    if (key > q) c[kg][r] = -1e30f;
                }
            }
        }
        // ---- online softmax row stats ----
        float mt[4];
#pragma unroll
        for (int r = 0; r < 4; r++) {
            float m0 = fmaxf(fmaxf(c[0][r], c[1][r]), fmaxf(c[2][r], c[3][r]));
            m0 = fmaxf(m0, __shfl_xor(m0, 1, 64));
            m0 = fmaxf(m0, __shfl_xor(m0, 2, 64));
            m0 = fmaxf(m0, __shfl_xor(m0, 4, 64));
            m0 = fmaxf(m0, __shfl_xor(m0, 8, 64));
            mt[r] = m0;
        }
        float alpha[4], rs[4];
#pragma unroll
        for (int r = 0; r < 4; r++) {
            const float m_new = fmaxf(m_run[r], mt[r]);
            alpha[r] = __expf(m_run[r] - m_new);
            m_run[r] = m_new;
            rs[r] = 0.f;
        }
        // ---- P = exp(S - m), stash bf16 strip in LDS (C layout -> rows) ----
#pragma unroll
        for (int kg = 0; kg < 4; kg++) {
#pragma unroll
            for (int r = 0; r < 4; r++) {
                const float p = __expf(c[kg][r] - m_run[r]);
                rs[r] += p;
                P_lds[wave][quad * 4 + r][kg * 16 + l16] = f2bf(p);
            }
        }
#pragma unroll
        for (int r = 0; r < 4; r++) {
            float s = rs[r];
            s += __shfl_xor(s, 1, 64);
            s += __shfl_xor(s, 2, 64);
            s += __shfl_xor(s, 4, 64);
            s += __shfl_xor(s, 8, 64);
            l_run[r] = l_run[r] * alpha[r] + s;
        }
        // ---- rescale O ----
#pragma unroll
        for (int hg = 0; hg < 4; hg++) {
#pragma unroll
            for (int r = 0; r < 4; r++) o[hg][r] *= alpha[r];
        }
        // ---- read P back in A layout ----
        asm volatile("s_waitcnt lgkmcnt(0)" ::: "memory");
        short8 ap0 = *(const short8*)&P_lds[wave][l16][quad * 8];
        short8 ap1 = *(const short8*)&P_lds[wave][l16][32 + quad * 8];
        // ---- O += P V ----
#pragma unroll
        for (int hg = 0; hg < 4; hg++) {
            const ushort* vrow = Vh + (size_t)(hg * 16 + l16) * SS + kb * 64 + quad * 8;
            short8 bv0 = *(const short8*)(vrow);
            short8 bv1 = *(const short8*)(vrow + 32);
            o[hg] = __builtin_amdgcn_mfma_f32_16x16x32_bf16(ap0, bv0, o[hg], 0, 0, 0);
            o[hg] = __builtin_amdgcn_mfma_f32_16x16x32_bf16(ap1, bv1, o[hg], 0, 0, 0);
        }
        asm volatile("s_waitcnt lgkmcnt(0)" ::: "memory");  // WAR: reads done before next overwrite
    }

    float inv[4];
#pragma unroll
    for (int r = 0; r < 4; r++) inv[r] = 1.f / l_run[r];
#pragma unroll
    for (int hg = 0; hg < 4; hg++) {
#pragma unroll
        for (int r = 0; r < 4; r++) {
            Z[hb + (size_t)(qbase + quad * 4 + r) * DH + hg * 16 + l16] = o[hg][r] * inv[r];
        }
    }
}

// ---------------- Kernel C: sum over heads GEMM ----------------
__global__ __launch_bounds__(256) void sum_gemm_k(
    const float* __restrict__ Z, const float* __restrict__ WO,
    const float* __restrict__ bO, float* __restrict__ out, float* __restrict__ sum1)
{
    __shared__ float As[16][68];
    __shared__ float Bs[16][68];
    const int tid = threadIdx.x;
    const int nt = blockIdx.x;    // 0..11
    const int mt = blockIdx.y;    // 0..15
    const int bp = blockIdx.z;    // 0..7

    const int mi = tid >> 2;
    const int k4 = (tid & 3) * 4;
    const float* zrow = Z + (size_t)bp * (NH * SS * DH) + (size_t)(mt * 64 + mi) * DH;

    const int bkk = tid >> 4;
    const int j4  = (tid & 15) * 4;
    const float* brow = WO + (size_t)bkk * DM + nt * 64 + j4;

    const int tx = tid & 15, ty = tid >> 4;
    float acc[4][4] = {};

    for (int kt = 0; kt < 48; kt++) {
        const int kk = kt * 16 + k4;
        float4 av = *(const float4*)(zrow + (size_t)(kk >> 6) * (SS * DH) + (kk & 63));
        float4 bv = *(const float4*)(brow + (size_t)kt * 16 * DM);
        __syncthreads();
        As[k4 + 0][mi] = av.x; As[k4 + 1][mi] = av.y;
        As[k4 + 2][mi] = av.z; As[k4 + 3][mi] = av.w;
        *(float4*)&Bs[bkk][j4] = bv;
        __syncthreads();
#pragma unroll
        for (int kk2 = 0; kk2 < 16; kk2++) {
            float4 a4 = *(const float4*)&As[kk2][ty * 4];
            float4 b4 = *(const float4*)&Bs[kk2][tx * 4];
            float aa[4] = {a4.x, a4.y, a4.z, a4.w};
            float bb[4] = {b4.x, b4.y, b4.z, b4.w};
#pragma unroll
            for (int i = 0; i < 4; i++)
#pragma unroll
                for (int j = 0; j < 4; j++)
                    acc[i][j] += aa[i] * bb[j];
        }
    }

    const int b_ = bp >> 1, pp = bp & 1;
#pragma unroll
    for (int i = 0; i < 4; i++) {
        const int q = mt * 64 + ty * 4 + i;
#pragma unroll
        for (int j = 0; j < 4; j++) {
            const int d = nt * 64 + tx * 4 + j;
            const float v = acc[i][j] + bO[d];
            out[(((size_t)b_ * 14 + pp) * SS + q) * DM + d] = v;
            if (pp) sum1[((size_t)b_ * SS + q) * DM + d] = v;
        }
    }
}

// ---------------- Kernel D: per-head diff GEMM + combine ----------------
__global__ __launch_bounds__(256) void headdiff_k(
    const float* __restrict__ Z, const float* __restrict__ WO,
    const float* __restrict__ sum1, float* __restrict__ out)
{
    __shared__ float As[16][68];
    __shared__ float Bs[16][68];
    const int tid = threadIdx.x;
    const int nt = blockIdx.x;    // 0..11
    const int mt = blockIdx.y;    // 0..15
    const int bk = blockIdx.z;    // 0..47
    const int b_ = bk / NH, k = bk % NH;

    const size_t z0 = ((size_t)(b_ * 2)     * NH + k) * (SS * DH);
    const size_t z1 = ((size_t)(b_ * 2 + 1) * NH + k) * (SS * DH);

    const int mi = tid >> 2;
    const int k4 = (tid & 3) * 4;
    const float* zr0 = Z + z0 + (size_t)(mt * 64 + mi) * DH;
    const float* zr1 = Z + z1 + (size_t)(mt * 64 + mi) * DH;

    const int bkk = tid >> 4;
    const int j4  = (tid & 15) * 4;
    const float* brow = WO + (size_t)k * (DH * DM) + (size_t)bkk * DM + nt * 64 + j4;

    const int tx = tid & 15, ty = tid >> 4;
    float acc[4][4] = {};

    for (int kt = 0; kt < 4; kt++) {
        float4 a0 = *(const float4*)(zr0 + kt * 16 + k4);
        float4 a1 = *(const float4*)(zr1 + kt * 16 + k4);
        float4 bv = *(const float4*)(brow + (size_t)kt * 16 * DM);
        __syncthreads();
        As[k4 + 0][mi] = a0.x - a1.x; As[k4 + 1][mi] = a0.y - a1.y;
        As[k4 + 2][mi] = a0.z - a1.z; As[k4 + 3][mi] = a0.w - a1.w;
        *(float4*)&Bs[bkk][j4] = bv;
        __syncthreads();
#pragma unroll
        for (int kk2 = 0; kk2 < 16; kk2++) {
            float4 a4 = *(const float4*)&As[kk2][ty * 4];
            float4 b4 = *(const float4*)&Bs[kk2][tx * 4];
            float aa[4] = {a4.x, a4.y, a4.z, a4.w};
            float bb[4] = {b4.x, b4.y, b4.z, b4.w};
#pragma unroll
            for (int i = 0; i < 4; i++)
#pragma unroll
                for (int j = 0; j < 4; j++)
                    acc[i][j] += aa[i] * bb[j];
        }
    }

#pragma unroll
    for (int i = 0; i < 4; i++) {
        const int q = mt * 64 + ty * 4 + i;
#pragma unroll
        for (int j = 0; j < 4; j++) {
            const int d = nt * 64 + tx * 4 + j;
            out[(((size_t)b_ * 14 + 2 + k) * SS + q) * DM + d] =
                acc[i][j] + sum1[((size_t)b_ * SS + q) * DM + d];
        }
    }
}

extern "C" void kernel_launch(void* const* d_in, const int* in_sizes, int n_in,
                              void* d_out, int out_size, void* d_ws, size_t ws_size,
                              hipStream_t stream)
{
    const float* x0 = (const float*)d_in[0];
    const float* x1 = (const float*)d_in[1];
    const float* WQ = (const float*)d_in[2];
    const float* bQ = (const float*)d_in[3];
    const float* WK = (const float*)d_in[4];
    const float* bK = (const float*)d_in[5];
    const float* WV = (const float*)d_in[6];
    const float* bV = (const float*)d_in[7];
    const float* WO = (const float*)d_in[8];
    const float* bO = (const float*)d_in[9];
    float* out = (float*)d_out;

    float* ws = (float*)d_ws;
    float*  Z    = ws;                        // 6291456 floats
    float*  sum1 = ws + 6291456;              // 3145728 floats
    ushort* Qb   = (ushort*)(ws + 9437184);   // 6291456 ushorts
    ushort* Kb   = Qb + 6291456;
    ushort* Vtb  = Kb + 6291456;

    qkv_gemm_k<<<dim3(36, 128), 256, 0, stream>>>(x0, x1, WQ, bQ, WK, bK, WV, bV, Qb, Kb, Vtb);
    attn_mfma_k<<<dim3(96, 16), 256, 0, stream>>>(Qb, Kb, Vtb, Z);
    sum_gemm_k<<<dim3(12, 16, 8), 256, 0, stream>>>(Z, WO, bO, out, sum1);
    headdiff_k<<<dim3(12, 16, 48), 256, 0, stream>>>(Z, WO, sum1, out);
}

// Round 3
// 555.972 us; speedup vs baseline: 5.3915x; 1.5741x over previous
//
#include <hip/hip_runtime.h>
#include <math.h>

#define NH 12
#define DM 768
#define DH 64
#define SS 1024

typedef __attribute__((ext_vector_type(8))) short short8;
typedef __attribute__((ext_vector_type(4))) float floatx4;
typedef __attribute__((ext_vector_type(4))) unsigned short usv4;

__device__ __forceinline__ ushort f2bf(float f) {
    union { float f; unsigned u; } v; v.f = f;
    unsigned r = v.u + 0x7fffu + ((v.u >> 16) & 1u);
    return (ushort)(r >> 16);
}

__device__ __forceinline__ void gld_lds16(const ushort* g, ushort* l) {
    __builtin_amdgcn_global_load_lds(
        (const __attribute__((address_space(1))) unsigned int*)g,
        (__attribute__((address_space(3))) unsigned int*)l, 16, 0, 0);
}

// ws layout:
//   Z    : fp32 [8 bp][12 n][1024 s][64 h]      @ float 0        (6291456 f)
//   sum1 : fp32 [4 b][1024 q][768 d]            @ float 6291456  (3145728 f)
//   then ushort region @ float 9437184:
//   Qb   : bf16 [8][12][1024][64] (x0.125)      +0
//   Kb   : bf16 [8][12][1024][64]               +6291456
//   Vtb  : bf16 [8][12][64][1024]               +12582912
//   xb   : bf16 [8192][768]                     +18874368
//   WbT  : bf16 [3][12 n][64 h][768 d]          +25165824  (1769472 u)

// ---------------- cast x -> bf16 ----------------
__global__ __launch_bounds__(256) void cast_x_k(
    const float* __restrict__ x0, const float* __restrict__ x1, ushort* __restrict__ xb)
{
    const size_t e = ((size_t)blockIdx.x * 256 + threadIdx.x) * 8;
    const int m = (int)(e / DM), col = (int)(e % DM);
    const int p = (m >> 10) & 1, b = m >> 11, s = m & 1023;
    const float* src = ((p == 0) ? x0 : x1) + (size_t)b * (SS * DM) + (size_t)s * DM + col;
    float4 v0 = *(const float4*)(src);
    float4 v1 = *(const float4*)(src + 4);
    short8 o;
    o[0] = (short)f2bf(v0.x); o[1] = (short)f2bf(v0.y); o[2] = (short)f2bf(v0.z); o[3] = (short)f2bf(v0.w);
    o[4] = (short)f2bf(v1.x); o[5] = (short)f2bf(v1.y); o[6] = (short)f2bf(v1.z); o[7] = (short)f2bf(v1.w);
    *(short8*)(xb + e) = o;
}

// ---------------- cast+transpose W -> bf16 [t][n][h][d] ----------------
__global__ __launch_bounds__(256) void cast_w_k(
    const float* __restrict__ WQ, const float* __restrict__ WK, const float* __restrict__ WV,
    ushort* __restrict__ WbT)
{
    __shared__ float T[64][68];
    const int tn = blockIdx.x;           // t*12+n
    const int dt = blockIdx.y;           // 0..11
    const int t = tn / NH, n = tn % NH;
    const float* W = ((t == 0) ? WQ : (t == 1) ? WK : WV) + (size_t)n * (DM * DH);
    const int d0 = dt * 64;
    const int tid = threadIdx.x;
    const int di = tid >> 2, cg = tid & 3;
#pragma unroll
    for (int j = 0; j < 4; j++) {
        const int c = cg * 16 + j * 4;
        float4 v = *(const float4*)(W + (size_t)(d0 + di) * DH + c);
        *(float4*)&T[di][c] = v;
    }
    __syncthreads();
    ushort* dst = WbT + (size_t)t * (NH * DH * DM) + (size_t)n * (DH * DM) + (size_t)di * DM + d0;
#pragma unroll
    for (int j = 0; j < 4; j++) {
        const int dc = cg * 16 + j * 4;
        usv4 o;
        o[0] = f2bf(T[dc + 0][di]); o[1] = f2bf(T[dc + 1][di]);
        o[2] = f2bf(T[dc + 2][di]); o[3] = f2bf(T[dc + 3][di]);
        *(usv4*)(dst + dc) = o;
    }
}

// ---------------- Kernel A: QKV MFMA GEMM ----------------
// C[8192 x 2304] = xb @ WbT^T ; 128x128 tiles; BK=32; async global->LDS staging.
__global__ __launch_bounds__(256) void qkv_mfma_k(
    const ushort* __restrict__ xb, const ushort* __restrict__ WbT,
    const float* __restrict__ bQ, const float* __restrict__ bK, const float* __restrict__ bV,
    ushort* __restrict__ Qb, ushort* __restrict__ Kb, ushort* __restrict__ Vtb)
{
    __shared__ ushort As[128 * 32];
    __shared__ ushort Bs[128 * 32];
    const int tid = threadIdx.x;
    const int w = tid >> 6, lane = tid & 63;
    const int l16 = lane & 15, quad = lane >> 4;
    const int jt = blockIdx.x;          // 0..17
    const int mt = blockIdx.y;          // 0..63
    const int t = jt / 6;
    const int jb = (jt % 6) * 128;      // col base within type t
    const int mbase = mt * 128;

    // B as [768 cols][768 k] for this t
    const ushort* Bt = WbT + (size_t)t * (DM * DM) + (size_t)jb * DM;

    // staging addresses: per wave-instr, 16 rows x 64B; lane l -> row l>>2, byte (l&3)*16
    const int srow = (lane >> 2);
    const int scol = (lane & 3) * 8;                 // ushort units
    const ushort* gA0 = xb + (size_t)(mbase + w * 32 + srow) * DM + scol;
    const ushort* gB0 = Bt + (size_t)(w * 32 + srow) * DM + scol;
    ushort* lA0 = As + (w * 32) * 32;
    ushort* lB0 = Bs + (w * 32) * 32;

    floatx4 acc[2][8];
#pragma unroll
    for (int m = 0; m < 2; m++)
#pragma unroll
        for (int n = 0; n < 8; n++) acc[m][n] = (floatx4){0.f, 0.f, 0.f, 0.f};

    for (int kt = 0; kt < 24; kt++) {
        const int k0 = kt * 32;
        __syncthreads();
        gld_lds16(gA0 + k0, lA0);
        gld_lds16(gA0 + (size_t)16 * DM + k0, lA0 + 16 * 32);
        gld_lds16(gB0 + k0, lB0);
        gld_lds16(gB0 + (size_t)16 * DM + k0, lB0 + 16 * 32);
        asm volatile("s_waitcnt vmcnt(0)" ::: "memory");
        __syncthreads();

        const ushort* Ab = As + (w * 32 + l16) * 32 + quad * 8;
        short8 a0 = *(const short8*)(Ab);
        short8 a1 = *(const short8*)(Ab + 16 * 32);
#pragma unroll
        for (int n = 0; n < 8; n++) {
            short8 b = *(const short8*)(Bs + (n * 16 + l16) * 32 + quad * 8);
            acc[0][n] = __builtin_amdgcn_mfma_f32_16x16x32_bf16(a0, b, acc[0][n], 0, 0, 0);
            acc[1][n] = __builtin_amdgcn_mfma_f32_16x16x32_bf16(a1, b, acc[1][n], 0, 0, 0);
        }
    }

    const float* bias = (t == 0) ? bQ : (t == 1) ? bK : bV;
#pragma unroll
    for (int m = 0; m < 2; m++) {
        const int mrow0 = mbase + w * 32 + m * 16 + quad * 4;   // +r
        const int bp = mrow0 >> 10;
        const int s0 = mrow0 & 1023;
#pragma unroll
        for (int n = 0; n < 8; n++) {
            const int col = jb + n * 16 + l16;      // 0..767 within t
            const int head = col >> 6, h = col & 63;
            const size_t hb = ((size_t)bp * NH + head) * (SS * DH);
            const float bv = bias[head * DH + h];
            if (t == 0) {
#pragma unroll
                for (int r = 0; r < 4; r++)
                    Qb[hb + (size_t)(s0 + r) * DH + h] = f2bf((acc[m][n][r] + bv) * 0.125f);
            } else if (t == 1) {
#pragma unroll
                for (int r = 0; r < 4; r++)
                    Kb[hb + (size_t)(s0 + r) * DH + h] = f2bf(acc[m][n][r] + bv);
            } else {
                usv4 o;
#pragma unroll
                for (int r = 0; r < 4; r++) o[r] = f2bf(acc[m][n][r] + bv);
                *(usv4*)(Vtb + hb + (size_t)h * SS + s0) = o;
            }
        }
    }
}

// ---------------- Kernel B: MFMA flash attention ----------------
__global__ __launch_bounds__(256) void attn_mfma_k(
    const ushort* __restrict__ Qb, const ushort* __restrict__ Kb,
    const ushort* __restrict__ Vtb, float* __restrict__ Z)
{
    __shared__ __align__(16) ushort P_lds[4][16][72];
    const int head = blockIdx.x;
    const int wave = threadIdx.x >> 6;
    const int lane = threadIdx.x & 63;
    const int quad = lane >> 4;
    const int l16  = lane & 15;
    const int qbase = blockIdx.y * 64 + wave * 16;

    const size_t hb = (size_t)head * (SS * DH);
    const ushort* Qh = Qb + hb;
    const ushort* Kh = Kb + hb;
    const ushort* Vh = Vtb + hb;

    short8 a_q0 = *(const short8*)(Qh + (size_t)(qbase + l16) * DH + quad * 8);
    short8 a_q1 = *(const short8*)(Qh + (size_t)(qbase + l16) * DH + 32 + quad * 8);

    floatx4 o[4];
    float m_run[4], l_run[4];
#pragma unroll
    for (int r = 0; r < 4; r++) {
        o[r] = (floatx4){0.f, 0.f, 0.f, 0.f};
        m_run[r] = -1e30f; l_run[r] = 0.f;
    }

    const int kb_last = (qbase + 15) >> 6;
    for (int kb = 0; kb <= kb_last; kb++) {
        floatx4 c[4];
#pragma unroll
        for (int kg = 0; kg < 4; kg++) {
            const ushort* krow = Kh + (size_t)(kb * 64 + kg * 16 + l16) * DH + quad * 8;
            short8 b0 = *(const short8*)(krow);
            short8 b1 = *(const short8*)(krow + 32);
            floatx4 cc = (floatx4){0.f, 0.f, 0.f, 0.f};
            cc = __builtin_amdgcn_mfma_f32_16x16x32_bf16(a_q0, b0, cc, 0, 0, 0);
            cc = __builtin_amdgcn_mfma_f32_16x16x32_bf16(a_q1, b1, cc, 0, 0, 0);
            c[kg] = cc;
        }
        if (kb == kb_last) {
#pragma unroll
            for (int kg = 0; kg < 4; kg++) {
                const int key = kb * 64 + kg * 16 + l16;
#pragma unroll
                for (int r = 0; r < 4; r++) {
                    const int q = qbase + quad * 4 + r;
                    if (key > q) c[kg][r] = -1e30f;
                }
            }
        }
        float mt_[4];
#pragma unroll
        for (int r = 0; r < 4; r++) {
            float m0 = fmaxf(fmaxf(c[0][r], c[1][r]), fmaxf(c[2][r], c[3][r]));
            m0 = fmaxf(m0, __shfl_xor(m0, 1, 64));
            m0 = fmaxf(m0, __shfl_xor(m0, 2, 64));
            m0 = fmaxf(m0, __shfl_xor(m0, 4, 64));
            m0 = fmaxf(m0, __shfl_xor(m0, 8, 64));
            mt_[r] = m0;
        }
        float alpha[4], rs[4];
#pragma unroll
        for (int r = 0; r < 4; r++) {
            const float m_new = fmaxf(m_run[r], mt_[r]);
            alpha[r] = __expf(m_run[r] - m_new);
            m_run[r] = m_new;
            rs[r] = 0.f;
        }
#pragma unroll
        for (int kg = 0; kg < 4; kg++) {
#pragma unroll
            for (int r = 0; r < 4; r++) {
                const float p = __expf(c[kg][r] - m_run[r]);
                rs[r] += p;
                P_lds[wave][quad * 4 + r][kg * 16 + l16] = f2bf(p);
            }
        }
#pragma unroll
        for (int r = 0; r < 4; r++) {
            float s = rs[r];
            s += __shfl_xor(s, 1, 64);
            s += __shfl_xor(s, 2, 64);
            s += __shfl_xor(s, 4, 64);
            s += __shfl_xor(s, 8, 64);
            l_run[r] = l_run[r] * alpha[r] + s;
        }
#pragma unroll
        for (int hg = 0; hg < 4; hg++) {
#pragma unroll
            for (int r = 0; r < 4; r++) o[hg][r] *= alpha[r];
        }
        asm volatile("s_waitcnt lgkmcnt(0)" ::: "memory");
        short8 ap0 = *(const short8*)&P_lds[wave][l16][quad * 8];
        short8 ap1 = *(const short8*)&P_lds[wave][l16][32 + quad * 8];
#pragma unroll
        for (int hg = 0; hg < 4; hg++) {
            const ushort* vrow = Vh + (size_t)(hg * 16 + l16) * SS + kb * 64 + quad * 8;
            short8 bv0 = *(const short8*)(vrow);
            short8 bv1 = *(const short8*)(vrow + 32);
            o[hg] = __builtin_amdgcn_mfma_f32_16x16x32_bf16(ap0, bv0, o[hg], 0, 0, 0);
            o[hg] = __builtin_amdgcn_mfma_f32_16x16x32_bf16(ap1, bv1, o[hg], 0, 0, 0);
        }
        asm volatile("s_waitcnt lgkmcnt(0)" ::: "memory");
    }

    float inv[4];
#pragma unroll
    for (int r = 0; r < 4; r++) inv[r] = 1.f / l_run[r];
#pragma unroll
    for (int hg = 0; hg < 4; hg++) {
#pragma unroll
        for (int r = 0; r < 4; r++) {
            Z[hb + (size_t)(qbase + quad * 4 + r) * DH + hg * 16 + l16] = o[hg][r] * inv[r];
        }
    }
}

// ---------------- Kernel C: sum over heads GEMM ----------------
__global__ __launch_bounds__(256) void sum_gemm_k(
    const float* __restrict__ Z, const float* __restrict__ WO,
    const float* __restrict__ bO, float* __restrict__ out, float* __restrict__ sum1)
{
    __shared__ float As[16][68];
    __shared__ float Bs[16][68];
    const int tid = threadIdx.x;
    const int nt = blockIdx.x;
    const int mt = blockIdx.y;
    const int bp = blockIdx.z;

    const int mi = tid >> 2;
    const int k4 = (tid & 3) * 4;
    const float* zrow = Z + (size_t)bp * (NH * SS * DH) + (size_t)(mt * 64 + mi) * DH;

    const int bkk = tid >> 4;
    const int j4  = (tid & 15) * 4;
    const float* brow = WO + (size_t)bkk * DM + nt * 64 + j4;

    const int tx = tid & 15, ty = tid >> 4;
    float acc[4][4] = {};

    for (int kt = 0; kt < 48; kt++) {
        const int kk = kt * 16 + k4;
        float4 av = *(const float4*)(zrow + (size_t)(kk >> 6) * (SS * DH) + (kk & 63));
        float4 bv = *(const float4*)(brow + (size_t)kt * 16 * DM);
        __syncthreads();
        As[k4 + 0][mi] = av.x; As[k4 + 1][mi] = av.y;
        As[k4 + 2][mi] = av.z; As[k4 + 3][mi] = av.w;
        *(float4*)&Bs[bkk][j4] = bv;
        __syncthreads();
#pragma unroll
        for (int kk2 = 0; kk2 < 16; kk2++) {
            float4 a4 = *(const float4*)&As[kk2][ty * 4];
            float4 b4 = *(const float4*)&Bs[kk2][tx * 4];
            float aa[4] = {a4.x, a4.y, a4.z, a4.w};
            float bb[4] = {b4.x, b4.y, b4.z, b4.w};
#pragma unroll
            for (int i = 0; i < 4; i++)
#pragma unroll
                for (int j = 0; j < 4; j++)
                    acc[i][j] += aa[i] * bb[j];
        }
    }

    const int b_ = bp >> 1, pp = bp & 1;
#pragma unroll
    for (int i = 0; i < 4; i++) {
        const int q = mt * 64 + ty * 4 + i;
#pragma unroll
        for (int j = 0; j < 4; j++) {
            const int d = nt * 64 + tx * 4 + j;
            const float v = acc[i][j] + bO[d];
            out[(((size_t)b_ * 14 + pp) * SS + q) * DM + d] = v;
            if (pp) sum1[((size_t)b_ * SS + q) * DM + d] = v;
        }
    }
}

// ---------------- Kernel D: per-head diff GEMM + combine ----------------
__global__ __launch_bounds__(256) void headdiff_k(
    const float* __restrict__ Z, const float* __restrict__ WO,
    const float* __restrict__ sum1, float* __restrict__ out)
{
    __shared__ float As[16][68];
    __shared__ float Bs[16][68];
    const int tid = threadIdx.x;
    const int nt = blockIdx.x;
    const int mt = blockIdx.y;
    const int bk = blockIdx.z;
    const int b_ = bk / NH, k = bk % NH;

    const size_t z0 = ((size_t)(b_ * 2)     * NH + k) * (SS * DH);
    const size_t z1 = ((size_t)(b_ * 2 + 1) * NH + k) * (SS * DH);

    const int mi = tid >> 2;
    const int k4 = (tid & 3) * 4;
    const float* zr0 = Z + z0 + (size_t)(mt * 64 + mi) * DH;
    const float* zr1 = Z + z1 + (size_t)(mt * 64 + mi) * DH;

    const int bkk = tid >> 4;
    const int j4  = (tid & 15) * 4;
    const float* brow = WO + (size_t)k * (DH * DM) + (size_t)bkk * DM + nt * 64 + j4;

    const int tx = tid & 15, ty = tid >> 4;
    float acc[4][4] = {};

    for (int kt = 0; kt < 4; kt++) {
        float4 a0 = *(const float4*)(zr0 + kt * 16 + k4);
        float4 a1 = *(const float4*)(zr1 + kt * 16 + k4);
        float4 bv = *(const float4*)(brow + (size_t)kt * 16 * DM);
        __syncthreads();
        As[k4 + 0][mi] = a0.x - a1.x; As[k4 + 1][mi] = a0.y - a1.y;
        As[k4 + 2][mi] = a0.z - a1.z; As[k4 + 3][mi] = a0.w - a1.w;
        *(float4*)&Bs[bkk][j4] = bv;
        __syncthreads();
#pragma unroll
        for (int kk2 = 0; kk2 < 16; kk2++) {
            float4 a4 = *(const float4*)&As[kk2][ty * 4];
            float4 b4 = *(const float4*)&Bs[kk2][tx * 4];
            float aa[4] = {a4.x, a4.y, a4.z, a4.w};
            float bb[4] = {b4.x, b4.y, b4.z, b4.w};
#pragma unroll
            for (int i = 0; i < 4; i++)
#pragma unroll
                for (int j = 0; j < 4; j++)
                    acc[i][j] += aa[i] * bb[j];
        }
    }

#pragma unroll
    for (int i = 0; i < 4; i++) {
        const int q = mt * 64 + ty * 4 + i;
#pragma unroll
        for (int j = 0; j < 4; j++) {
            const int d = nt * 64 + tx * 4 + j;
            out[(((size_t)b_ * 14 + 2 + k) * SS + q) * DM + d] =
                acc[i][j] + sum1[((size_t)b_ * SS + q) * DM + d];
        }
    }
}

extern "C" void kernel_launch(void* const* d_in, const int* in_sizes, int n_in,
                              void* d_out, int out_size, void* d_ws, size_t ws_size,
                              hipStream_t stream)
{
    const float* x0 = (const float*)d_in[0];
    const float* x1 = (const float*)d_in[1];
    const float* WQ = (const float*)d_in[2];
    const float* bQ = (const float*)d_in[3];
    const float* WK = (const float*)d_in[4];
    const float* bK = (const float*)d_in[5];
    const float* WV = (const float*)d_in[6];
    const float* bV = (const float*)d_in[7];
    const float* WO = (const float*)d_in[8];
    const float* bO = (const float*)d_in[9];
    float* out = (float*)d_out;

    float* ws = (float*)d_ws;
    float*  Z    = ws;                        // 6291456 f
    float*  sum1 = ws + 6291456;              // 3145728 f
    ushort* ub   = (ushort*)(ws + 9437184);
    ushort* Qb   = ub;                        // 6291456 u
    ushort* Kb   = Qb + 6291456;
    ushort* Vtb  = Kb + 6291456;
    ushort* xb   = Vtb + 6291456;             // 6291456 u
    ushort* WbT  = xb + 6291456;              // 1769472 u

    cast_x_k<<<dim3(3072), 256, 0, stream>>>(x0, x1, xb);
    cast_w_k<<<dim3(36, 12), 256, 0, stream>>>(WQ, WK, WV, WbT);
    qkv_mfma_k<<<dim3(18, 64), 256, 0, stream>>>(xb, WbT, bQ, bK, bV, Qb, Kb, Vtb);
    attn_mfma_k<<<dim3(96, 16), 256, 0, stream>>>(Qb, Kb, Vtb, Z);
    sum_gemm_k<<<dim3(12, 16, 8), 256, 0, stream>>>(Z, WO, bO, out, sum1);
    headdiff_k<<<dim3(12, 16, 48), 256, 0, stream>>>(Z, WO, sum1, out);
}

// Round 4
// 456.810 us; speedup vs baseline: 6.5619x; 1.2171x over previous
//
#include <hip/hip_runtime.h>
#include <math.h>

#define NH 12
#define DM 768
#define DH 64
#define SS 1024

typedef __attribute__((ext_vector_type(8))) short short8;
typedef __attribute__((ext_vector_type(4))) float floatx4;
typedef __attribute__((ext_vector_type(4))) unsigned short usv4;

__device__ __forceinline__ ushort f2bf(float f) {
    union { float f; unsigned u; } v; v.f = f;
    unsigned r = v.u + 0x7fffu + ((v.u >> 16) & 1u);
    return (ushort)(r >> 16);
}
__device__ __forceinline__ float bf2f(ushort u) {
    union { unsigned u; float f; } v; v.u = ((unsigned)u) << 16;
    return v.f;
}

__device__ __forceinline__ void gld_lds16(const ushort* g, ushort* l) {
    __builtin_amdgcn_global_load_lds(
        (const __attribute__((address_space(1))) unsigned int*)g,
        (__attribute__((address_space(3))) unsigned int*)l, 16, 0, 0);
}

// ws layout (ushort units):
//   Qb   : bf16 [8][12][1024][64] (x0.125)   @ 0          (6291456)
//   Kb   : bf16 [8][12][1024][64]            @ 6291456
//   Vtb  : bf16 [8][12][64][1024]            @ 12582912
//   xb   : bf16 [8192][768]                  @ 18874368
//   WbT  : bf16 [3][12 n][64 h][768 d]       @ 25165824   (1769472)
//   Zb   : bf16 [8 bp][12 n][1024 s][64 h]   @ 26935296   (6291456)
//   WObT : bf16 [768 d][768 k=(n,h)]         @ 33226752   (589824)
//   Zd   : bf16 [4 b][12 n][1024 s][64 h]    @ 33816576   (3145728)

// ---------------- cast x -> bf16 ----------------
__global__ __launch_bounds__(256) void cast_x_k(
    const float* __restrict__ x0, const float* __restrict__ x1, ushort* __restrict__ xb)
{
    const size_t e = ((size_t)blockIdx.x * 256 + threadIdx.x) * 8;
    const int m = (int)(e / DM), col = (int)(e % DM);
    const int p = (m >> 10) & 1, b = m >> 11, s = m & 1023;
    const float* src = ((p == 0) ? x0 : x1) + (size_t)b * (SS * DM) + (size_t)s * DM + col;
    float4 v0 = *(const float4*)(src);
    float4 v1 = *(const float4*)(src + 4);
    short8 o;
    o[0] = (short)f2bf(v0.x); o[1] = (short)f2bf(v0.y); o[2] = (short)f2bf(v0.z); o[3] = (short)f2bf(v0.w);
    o[4] = (short)f2bf(v1.x); o[5] = (short)f2bf(v1.y); o[6] = (short)f2bf(v1.z); o[7] = (short)f2bf(v1.w);
    *(short8*)(xb + e) = o;
}

// ---------------- cast+transpose QKV weights -> bf16 [t][n][h][d] ----------------
__global__ __launch_bounds__(256) void cast_w_k(
    const float* __restrict__ WQ, const float* __restrict__ WK, const float* __restrict__ WV,
    ushort* __restrict__ WbT)
{
    __shared__ float T[64][68];
    const int tn = blockIdx.x;           // t*12+n
    const int dt = blockIdx.y;           // 0..11
    const int t = tn / NH, n = tn % NH;
    const float* W = ((t == 0) ? WQ : (t == 1) ? WK : WV) + (size_t)n * (DM * DH);
    const int d0 = dt * 64;
    const int tid = threadIdx.x;
    const int di = tid >> 2, cg = tid & 3;
#pragma unroll
    for (int j = 0; j < 4; j++) {
        const int c = cg * 16 + j * 4;
        float4 v = *(const float4*)(W + (size_t)(d0 + di) * DH + c);
        *(float4*)&T[di][c] = v;
    }
    __syncthreads();
    ushort* dst = WbT + (size_t)t * (NH * DH * DM) + (size_t)n * (DH * DM) + (size_t)di * DM + d0;
#pragma unroll
    for (int j = 0; j < 4; j++) {
        const int dc = cg * 16 + j * 4;
        usv4 o;
        o[0] = f2bf(T[dc + 0][di]); o[1] = f2bf(T[dc + 1][di]);
        o[2] = f2bf(T[dc + 2][di]); o[3] = f2bf(T[dc + 3][di]);
        *(usv4*)(dst + dc) = o;
    }
}

// ---------------- cast+transpose WO -> bf16 [d][k] ----------------
__global__ __launch_bounds__(256) void cast_wo_k(
    const float* __restrict__ WO, ushort* __restrict__ WObT)
{
    __shared__ float T[64][68];
    const int kt = blockIdx.x;           // 0..11 (k-tile)
    const int dt = blockIdx.y;           // 0..11 (d-tile)
    const int tid = threadIdx.x;
    const int di = tid >> 2, cg = tid & 3;
#pragma unroll
    for (int j = 0; j < 4; j++) {
        const int c = cg * 16 + j * 4;
        float4 v = *(const float4*)(WO + (size_t)(kt * 64 + di) * DM + dt * 64 + c);
        *(float4*)&T[di][c] = v;
    }
    __syncthreads();
    ushort* dst = WObT + (size_t)(dt * 64 + di) * DM + kt * 64;
#pragma unroll
    for (int j = 0; j < 4; j++) {
        const int dc = cg * 16 + j * 4;
        usv4 o;
        o[0] = f2bf(T[dc + 0][di]); o[1] = f2bf(T[dc + 1][di]);
        o[2] = f2bf(T[dc + 2][di]); o[3] = f2bf(T[dc + 3][di]);
        *(usv4*)(dst + dc) = o;
    }
}

// ---------------- Kernel A: QKV MFMA GEMM ----------------
__global__ __launch_bounds__(256) void qkv_mfma_k(
    const ushort* __restrict__ xb, const ushort* __restrict__ WbT,
    const float* __restrict__ bQ, const float* __restrict__ bK, const float* __restrict__ bV,
    ushort* __restrict__ Qb, ushort* __restrict__ Kb, ushort* __restrict__ Vtb)
{
    __shared__ ushort As[128 * 32];
    __shared__ ushort Bs[128 * 32];
    const int tid = threadIdx.x;
    const int w = tid >> 6, lane = tid & 63;
    const int l16 = lane & 15, quad = lane >> 4;
    const int jt = blockIdx.x;          // 0..17
    const int mt = blockIdx.y;          // 0..63
    const int t = jt / 6;
    const int jb = (jt % 6) * 128;
    const int mbase = mt * 128;

    const ushort* Bt = WbT + (size_t)t * (DM * DM) + (size_t)jb * DM;

    const int srow = (lane >> 2);
    const int scol = (lane & 3) * 8;
    const ushort* gA0 = xb + (size_t)(mbase + w * 32 + srow) * DM + scol;
    const ushort* gB0 = Bt + (size_t)(w * 32 + srow) * DM + scol;
    ushort* lA0 = As + (w * 32) * 32;
    ushort* lB0 = Bs + (w * 32) * 32;

    floatx4 acc[2][8];
#pragma unroll
    for (int m = 0; m < 2; m++)
#pragma unroll
        for (int n = 0; n < 8; n++) acc[m][n] = (floatx4){0.f, 0.f, 0.f, 0.f};

    for (int kt = 0; kt < 24; kt++) {
        const int k0 = kt * 32;
        __syncthreads();
        gld_lds16(gA0 + k0, lA0);
        gld_lds16(gA0 + (size_t)16 * DM + k0, lA0 + 16 * 32);
        gld_lds16(gB0 + k0, lB0);
        gld_lds16(gB0 + (size_t)16 * DM + k0, lB0 + 16 * 32);
        asm volatile("s_waitcnt vmcnt(0)" ::: "memory");
        __syncthreads();

        const ushort* Ab = As + (w * 32 + l16) * 32 + quad * 8;
        short8 a0 = *(const short8*)(Ab);
        short8 a1 = *(const short8*)(Ab + 16 * 32);
#pragma unroll
        for (int n = 0; n < 8; n++) {
            short8 b = *(const short8*)(Bs + (n * 16 + l16) * 32 + quad * 8);
            acc[0][n] = __builtin_amdgcn_mfma_f32_16x16x32_bf16(a0, b, acc[0][n], 0, 0, 0);
            acc[1][n] = __builtin_amdgcn_mfma_f32_16x16x32_bf16(a1, b, acc[1][n], 0, 0, 0);
        }
    }

    const float* bias = (t == 0) ? bQ : (t == 1) ? bK : bV;
#pragma unroll
    for (int m = 0; m < 2; m++) {
        const int mrow0 = mbase + w * 32 + m * 16 + quad * 4;
        const int bp = mrow0 >> 10;
        const int s0 = mrow0 & 1023;
#pragma unroll
        for (int n = 0; n < 8; n++) {
            const int col = jb + n * 16 + l16;
            const int head = col >> 6, h = col & 63;
            const size_t hb = ((size_t)bp * NH + head) * (SS * DH);
            const float bv = bias[head * DH + h];
            if (t == 0) {
#pragma unroll
                for (int r = 0; r < 4; r++)
                    Qb[hb + (size_t)(s0 + r) * DH + h] = f2bf((acc[m][n][r] + bv) * 0.125f);
            } else if (t == 1) {
#pragma unroll
                for (int r = 0; r < 4; r++)
                    Kb[hb + (size_t)(s0 + r) * DH + h] = f2bf(acc[m][n][r] + bv);
            } else {
                usv4 o;
#pragma unroll
                for (int r = 0; r < 4; r++) o[r] = f2bf(acc[m][n][r] + bv);
                *(usv4*)(Vtb + hb + (size_t)h * SS + s0) = o;
            }
        }
    }
}

// ---------------- Kernel B: MFMA flash attention (bf16 Z out) ----------------
__global__ __launch_bounds__(256) void attn_mfma_k(
    const ushort* __restrict__ Qb, const ushort* __restrict__ Kb,
    const ushort* __restrict__ Vtb, ushort* __restrict__ Zb)
{
    __shared__ __align__(16) ushort P_lds[4][16][72];
    const int head = blockIdx.x;
    const int wave = threadIdx.x >> 6;
    const int lane = threadIdx.x & 63;
    const int quad = lane >> 4;
    const int l16  = lane & 15;
    const int qbase = blockIdx.y * 64 + wave * 16;

    const size_t hb = (size_t)head * (SS * DH);
    const ushort* Qh = Qb + hb;
    const ushort* Kh = Kb + hb;
    const ushort* Vh = Vtb + hb;

    short8 a_q0 = *(const short8*)(Qh + (size_t)(qbase + l16) * DH + quad * 8);
    short8 a_q1 = *(const short8*)(Qh + (size_t)(qbase + l16) * DH + 32 + quad * 8);

    floatx4 o[4];
    float m_run[4], l_run[4];
#pragma unroll
    for (int r = 0; r < 4; r++) {
        o[r] = (floatx4){0.f, 0.f, 0.f, 0.f};
        m_run[r] = -1e30f; l_run[r] = 0.f;
    }

    const int kb_last = (qbase + 15) >> 6;
    for (int kb = 0; kb <= kb_last; kb++) {
        floatx4 c[4];
#pragma unroll
        for (int kg = 0; kg < 4; kg++) {
            const ushort* krow = Kh + (size_t)(kb * 64 + kg * 16 + l16) * DH + quad * 8;
            short8 b0 = *(const short8*)(krow);
            short8 b1 = *(const short8*)(krow + 32);
            floatx4 cc = (floatx4){0.f, 0.f, 0.f, 0.f};
            cc = __builtin_amdgcn_mfma_f32_16x16x32_bf16(a_q0, b0, cc, 0, 0, 0);
            cc = __builtin_amdgcn_mfma_f32_16x16x32_bf16(a_q1, b1, cc, 0, 0, 0);
            c[kg] = cc;
        }
        if (kb == kb_last) {
#pragma unroll
            for (int kg = 0; kg < 4; kg++) {
                const int key = kb * 64 + kg * 16 + l16;
#pragma unroll
                for (int r = 0; r < 4; r++) {
                    const int q = qbase + quad * 4 + r;
                    if (key > q) c[kg][r] = -1e30f;
                }
            }
        }
        float mt_[4];
#pragma unroll
        for (int r = 0; r < 4; r++) {
            float m0 = fmaxf(fmaxf(c[0][r], c[1][r]), fmaxf(c[2][r], c[3][r]));
            m0 = fmaxf(m0, __shfl_xor(m0, 1, 64));
            m0 = fmaxf(m0, __shfl_xor(m0, 2, 64));
            m0 = fmaxf(m0, __shfl_xor(m0, 4, 64));
            m0 = fmaxf(m0, __shfl_xor(m0, 8, 64));
            mt_[r] = m0;
        }
        float alpha[4], rs[4];
#pragma unroll
        for (int r = 0; r < 4; r++) {
            const float m_new = fmaxf(m_run[r], mt_[r]);
            alpha[r] = __expf(m_run[r] - m_new);
            m_run[r] = m_new;
            rs[r] = 0.f;
        }
#pragma unroll
        for (int kg = 0; kg < 4; kg++) {
#pragma unroll
            for (int r = 0; r < 4; r++) {
                const float p = __expf(c[kg][r] - m_run[r]);
                rs[r] += p;
                P_lds[wave][quad * 4 + r][kg * 16 + l16] = f2bf(p);
            }
        }
#pragma unroll
        for (int r = 0; r < 4; r++) {
            float s = rs[r];
            s += __shfl_xor(s, 1, 64);
            s += __shfl_xor(s, 2, 64);
            s += __shfl_xor(s, 4, 64);
            s += __shfl_xor(s, 8, 64);
            l_run[r] = l_run[r] * alpha[r] + s;
        }
#pragma unroll
        for (int hg = 0; hg < 4; hg++) {
#pragma unroll
            for (int r = 0; r < 4; r++) o[hg][r] *= alpha[r];
        }
        asm volatile("s_waitcnt lgkmcnt(0)" ::: "memory");
        short8 ap0 = *(const short8*)&P_lds[wave][l16][quad * 8];
        short8 ap1 = *(const short8*)&P_lds[wave][l16][32 + quad * 8];
#pragma unroll
        for (int hg = 0; hg < 4; hg++) {
            const ushort* vrow = Vh + (size_t)(hg * 16 + l16) * SS + kb * 64 + quad * 8;
            short8 bv0 = *(const short8*)(vrow);
            short8 bv1 = *(const short8*)(vrow + 32);
            o[hg] = __builtin_amdgcn_mfma_f32_16x16x32_bf16(ap0, bv0, o[hg], 0, 0, 0);
            o[hg] = __builtin_amdgcn_mfma_f32_16x16x32_bf16(ap1, bv1, o[hg], 0, 0, 0);
        }
        asm volatile("s_waitcnt lgkmcnt(0)" ::: "memory");
    }

    float inv[4];
#pragma unroll
    for (int r = 0; r < 4; r++) inv[r] = 1.f / l_run[r];
#pragma unroll
    for (int hg = 0; hg < 4; hg++) {
#pragma unroll
        for (int r = 0; r < 4; r++) {
            Zb[hb + (size_t)(qbase + quad * 4 + r) * DH + hg * 16 + l16] = f2bf(o[hg][r] * inv[r]);
        }
    }
}

// ---------------- Zd = Z(p=0) - Z(p=1) per head ----------------
__global__ __launch_bounds__(256) void zdiff_k(
    const ushort* __restrict__ Zb, ushort* __restrict__ Zd)
{
    const size_t e = ((size_t)blockIdx.x * 256 + threadIdx.x) * 8;
    const int bk = (int)(e >> 16);           // b*12+k
    const int off = (int)(e & 65535);
    const int b_ = bk / NH, k = bk % NH;
    const ushort* z0 = Zb + ((size_t)(b_ * 2) * NH + k) * (SS * DH) + off;
    const ushort* z1 = Zb + ((size_t)(b_ * 2 + 1) * NH + k) * (SS * DH) + off;
    short8 a = *(const short8*)z0;
    short8 c = *(const short8*)z1;
    short8 o;
#pragma unroll
    for (int i = 0; i < 8; i++)
        o[i] = (short)f2bf(bf2f((ushort)a[i]) - bf2f((ushort)c[i]));
    *(short8*)(Zd + e) = o;
}

// ---------------- Kernel C: sum-over-heads MFMA GEMM ----------------
// out[b,p] = Zb_bp (1024 x 768,(n,h)) @ WObT^T + bO
__global__ __launch_bounds__(256) void sumo_mfma_k(
    const ushort* __restrict__ Zb, const ushort* __restrict__ WObT,
    const float* __restrict__ bO, float* __restrict__ out)
{
    __shared__ ushort As[128 * 32];
    __shared__ ushort Bs[128 * 32];
    const int tid = threadIdx.x;
    const int w = tid >> 6, lane = tid & 63;
    const int l16 = lane & 15, quad = lane >> 4;
    const int nt = blockIdx.x;          // 0..5
    const int mt = blockIdx.y;          // 0..63
    const int jb = nt * 128;
    const int mbase = mt * 128;
    const int bp = mbase >> 10;
    const int sb = mbase & 1023;

    const ushort* Zbp = Zb + (size_t)bp * (NH * SS * DH);
    const int srow = (lane >> 2);
    const int scol = (lane & 3) * 8;
    const int s_row = sb + w * 32 + srow;
    const ushort* gB0 = WObT + (size_t)(jb + w * 32 + srow) * DM + scol;
    ushort* lA0 = As + (w * 32) * 32;
    ushort* lB0 = Bs + (w * 32) * 32;

    floatx4 acc[2][8];
#pragma unroll
    for (int m = 0; m < 2; m++)
#pragma unroll
        for (int n = 0; n < 8; n++) acc[m][n] = (floatx4){0.f, 0.f, 0.f, 0.f};

    for (int kt = 0; kt < 24; kt++) {
        const int k0 = kt * 32;
        const ushort* gA = Zbp + (size_t)(k0 >> 6) * (SS * DH) + (size_t)s_row * DH + (k0 & 63) + scol;
        __syncthreads();
        gld_lds16(gA, lA0);
        gld_lds16(gA + (size_t)16 * DH, lA0 + 16 * 32);
        gld_lds16(gB0 + k0, lB0);
        gld_lds16(gB0 + (size_t)16 * DM + k0, lB0 + 16 * 32);
        asm volatile("s_waitcnt vmcnt(0)" ::: "memory");
        __syncthreads();

        const ushort* Ab = As + (w * 32 + l16) * 32 + quad * 8;
        short8 a0 = *(const short8*)(Ab);
        short8 a1 = *(const short8*)(Ab + 16 * 32);
#pragma unroll
        for (int n = 0; n < 8; n++) {
            short8 b = *(const short8*)(Bs + (n * 16 + l16) * 32 + quad * 8);
            acc[0][n] = __builtin_amdgcn_mfma_f32_16x16x32_bf16(a0, b, acc[0][n], 0, 0, 0);
            acc[1][n] = __builtin_amdgcn_mfma_f32_16x16x32_bf16(a1, b, acc[1][n], 0, 0, 0);
        }
    }

    const int b_ = bp >> 1, pp = bp & 1;
    float* obase = out + (((size_t)b_ * 14 + pp) * SS) * DM;
#pragma unroll
    for (int m = 0; m < 2; m++) {
        const int q0 = sb + w * 32 + m * 16 + quad * 4;
#pragma unroll
        for (int n = 0; n < 8; n++) {
            const int d = jb + n * 16 + l16;
            const float bv = bO[d];
#pragma unroll
            for (int r = 0; r < 4; r++)
                obase[(size_t)(q0 + r) * DM + d] = acc[m][n][r] + bv;
        }
    }
}

// ---------------- Kernel D: per-head diff MFMA GEMM + combine ----------------
// out[b,2+k] = Zd_bk (1024 x 64) @ WO[k] + out[b,1]
__global__ __launch_bounds__(256) void headdiff_mfma_k(
    const ushort* __restrict__ Zd, const ushort* __restrict__ WObT,
    float* __restrict__ out)
{
    __shared__ ushort As[128 * 32];
    __shared__ ushort Bs[128 * 32];
    const int tid = threadIdx.x;
    const int w = tid >> 6, lane = tid & 63;
    const int l16 = lane & 15, quad = lane >> 4;
    const int nt = blockIdx.x;          // 0..5
    const int mt = blockIdx.y;          // 0..7
    const int bk = blockIdx.z;          // 0..47
    const int b_ = bk / NH, k = bk % NH;
    const int jb = nt * 128;
    const int mbase = mt * 128;

    const ushort* Zdk = Zd + ((size_t)b_ * NH + k) * (SS * DH);
    const int srow = (lane >> 2);
    const int scol = (lane & 3) * 8;
    const ushort* gA0 = Zdk + (size_t)(mbase + w * 32 + srow) * DH + scol;
    const ushort* gB0 = WObT + (size_t)(jb + w * 32 + srow) * DM + k * DH + scol;
    ushort* lA0 = As + (w * 32) * 32;
    ushort* lB0 = Bs + (w * 32) * 32;

    floatx4 acc[2][8];
#pragma unroll
    for (int m = 0; m < 2; m++)
#pragma unroll
        for (int n = 0; n < 8; n++) acc[m][n] = (floatx4){0.f, 0.f, 0.f, 0.f};

#pragma unroll
    for (int kt = 0; kt < 2; kt++) {
        const int k0 = kt * 32;
        __syncthreads();
        gld_lds16(gA0 + k0, lA0);
        gld_lds16(gA0 + (size_t)16 * DH + k0, lA0 + 16 * 32);
        gld_lds16(gB0 + k0, lB0);
        gld_lds16(gB0 + (size_t)16 * DM + k0, lB0 + 16 * 32);
        asm volatile("s_waitcnt vmcnt(0)" ::: "memory");
        __syncthreads();

        const ushort* Ab = As + (w * 32 + l16) * 32 + quad * 8;
        short8 a0 = *(const short8*)(Ab);
        short8 a1 = *(const short8*)(Ab + 16 * 32);
#pragma unroll
        for (int n = 0; n < 8; n++) {
            short8 b = *(const short8*)(Bs + (n * 16 + l16) * 32 + quad * 8);
            acc[0][n] = __builtin_amdgcn_mfma_f32_16x16x32_bf16(a0, b, acc[0][n], 0, 0, 0);
            acc[1][n] = __builtin_amdgcn_mfma_f32_16x16x32_bf16(a1, b, acc[1][n], 0, 0, 0);
        }
    }

    const float* sum1 = out + (((size_t)b_ * 14 + 1) * SS) * DM;
    float* obase = out + (((size_t)b_ * 14 + 2 + k) * SS) * DM;
#pragma unroll
    for (int m = 0; m < 2; m++) {
        const int q0 = mbase + w * 32 + m * 16 + quad * 4;
#pragma unroll
        for (int n = 0; n < 8; n++) {
            const int d = jb + n * 16 + l16;
#pragma unroll
            for (int r = 0; r < 4; r++)
                obase[(size_t)(q0 + r) * DM + d] =
                    acc[m][n][r] + sum1[(size_t)(q0 + r) * DM + d];
        }
    }
}

extern "C" void kernel_launch(void* const* d_in, const int* in_sizes, int n_in,
                              void* d_out, int out_size, void* d_ws, size_t ws_size,
                              hipStream_t stream)
{
    const float* x0 = (const float*)d_in[0];
    const float* x1 = (const float*)d_in[1];
    const float* WQ = (const float*)d_in[2];
    const float* bQ = (const float*)d_in[3];
    const float* WK = (const float*)d_in[4];
    const float* bK = (const float*)d_in[5];
    const float* WV = (const float*)d_in[6];
    const float* bV = (const float*)d_in[7];
    const float* WO = (const float*)d_in[8];
    const float* bO = (const float*)d_in[9];
    float* out = (float*)d_out;

    ushort* ub   = (ushort*)d_ws;
    ushort* Qb   = ub;                        // 6291456
    ushort* Kb   = Qb + 6291456;
    ushort* Vtb  = Kb + 6291456;
    ushort* xb   = Vtb + 6291456;
    ushort* WbT  = xb + 6291456;              // 1769472
    ushort* Zb   = WbT + 1769472;             // 6291456
    ushort* WObT = Zb + 6291456;              // 589824
    ushort* Zd   = WObT + 589824;             // 3145728

    cast_x_k<<<dim3(3072), 256, 0, stream>>>(x0, x1, xb);
    cast_w_k<<<dim3(36, 12), 256, 0, stream>>>(WQ, WK, WV, WbT);
    cast_wo_k<<<dim3(12, 12), 256, 0, stream>>>(WO, WObT);
    qkv_mfma_k<<<dim3(18, 64), 256, 0, stream>>>(xb, WbT, bQ, bK, bV, Qb, Kb, Vtb);
    attn_mfma_k<<<dim3(96, 16), 256, 0, stream>>>(Qb, Kb, Vtb, Zb);
    zdiff_k<<<dim3(1536), 256, 0, stream>>>(Zb, Zd);
    sumo_mfma_k<<<dim3(6, 64), 256, 0, stream>>>(Zb, WObT, bO, out);
    headdiff_mfma_k<<<dim3(6, 8, 48), 256, 0, stream>>>(Zd, WObT, out);
}

// Round 5
// 425.284 us; speedup vs baseline: 7.0483x; 1.0741x over previous
//
#include <hip/hip_runtime.h>
#include <math.h>

#define NH 12
#define DM 768
#define DH 64
#define SS 1024

typedef __attribute__((ext_vector_type(8))) short short8;
typedef __attribute__((ext_vector_type(4))) float floatx4;
typedef __attribute__((ext_vector_type(4))) unsigned short usv4;

__device__ __forceinline__ ushort f2bf(float f) {
    union { float f; unsigned u; } v; v.f = f;
    unsigned r = v.u + 0x7fffu + ((v.u >> 16) & 1u);
    return (ushort)(r >> 16);
}
__device__ __forceinline__ float bf2f(ushort u) {
    union { unsigned u; float f; } v; v.u = ((unsigned)u) << 16;
    return v.f;
}

__device__ __forceinline__ void gld_lds16(const ushort* g, ushort* l) {
    __builtin_amdgcn_global_load_lds(
        (const __attribute__((address_space(1))) unsigned int*)g,
        (__attribute__((address_space(3))) unsigned int*)l, 16, 0, 0);
}

// ws layout (ushort units):
//   Qb   : bf16 [8][12][1024][64] (x0.125)   @ 0          (6291456)
//   Kb   : bf16 [8][12][1024][64]            @ 6291456
//   Vtb  : bf16 [8][12][64][1024]            @ 12582912
//   xb   : bf16 [8192][768]                  @ 18874368
//   WbT  : bf16 [3][12 n][64 h][768 d]       @ 25165824   (1769472)
//   Zb   : bf16 [8 bp][12 n][1024 s][64 h]   @ 26935296   (6291456)
//   WObT : bf16 [768 d][768 k=(n,h)]         @ 33226752   (589824)
//   Zd   : bf16 [4 b][12 n][1024 s][64 h]    @ 33816576   (3145728)

// ---------------- prep: all input casts in one kernel ----------------
// blocks 0..3071: x -> bf16 ; 3072..3503: QKV W cast+transpose ; 3504..3647: WO cast+transpose
__global__ __launch_bounds__(256) void prep_k(
    const float* __restrict__ x0, const float* __restrict__ x1,
    const float* __restrict__ WQ, const float* __restrict__ WK, const float* __restrict__ WV,
    const float* __restrict__ WO,
    ushort* __restrict__ xb, ushort* __restrict__ WbT, ushort* __restrict__ WObT)
{
    __shared__ float T[64][68];
    const int bid = blockIdx.x;
    const int tid = threadIdx.x;
    if (bid < 3072) {
        const size_t e = ((size_t)bid * 256 + tid) * 8;
        const int m = (int)(e / DM), col = (int)(e % DM);
        const int p = (m >> 10) & 1, b = m >> 11, s = m & 1023;
        const float* src = ((p == 0) ? x0 : x1) + (size_t)b * (SS * DM) + (size_t)s * DM + col;
        float4 v0 = *(const float4*)(src);
        float4 v1 = *(const float4*)(src + 4);
        short8 o;
        o[0] = (short)f2bf(v0.x); o[1] = (short)f2bf(v0.y); o[2] = (short)f2bf(v0.z); o[3] = (short)f2bf(v0.w);
        o[4] = (short)f2bf(v1.x); o[5] = (short)f2bf(v1.y); o[6] = (short)f2bf(v1.z); o[7] = (short)f2bf(v1.w);
        *(short8*)(xb + e) = o;
        return;
    }
    const int di = tid >> 2, cg = tid & 3;
    if (bid < 3072 + 432) {
        const int idx = bid - 3072;
        const int tn = idx % 36, dt = idx / 36;
        const int t = tn / NH, n = tn % NH;
        const float* W = ((t == 0) ? WQ : (t == 1) ? WK : WV) + (size_t)n * (DM * DH);
        const int d0 = dt * 64;
#pragma unroll
        for (int j = 0; j < 4; j++) {
            const int c = cg * 16 + j * 4;
            float4 v = *(const float4*)(W + (size_t)(d0 + di) * DH + c);
            *(float4*)&T[di][c] = v;
        }
        __syncthreads();
        ushort* dst = WbT + (size_t)t * (NH * DH * DM) + (size_t)n * (DH * DM) + (size_t)di * DM + d0;
#pragma unroll
        for (int j = 0; j < 4; j++) {
            const int dc = cg * 16 + j * 4;
            usv4 o;
            o[0] = f2bf(T[dc + 0][di]); o[1] = f2bf(T[dc + 1][di]);
            o[2] = f2bf(T[dc + 2][di]); o[3] = f2bf(T[dc + 3][di]);
            *(usv4*)(dst + dc) = o;
        }
        return;
    }
    {
        const int idx = bid - 3072 - 432;
        const int kt = idx % 12, dt = idx / 12;
#pragma unroll
        for (int j = 0; j < 4; j++) {
            const int c = cg * 16 + j * 4;
            float4 v = *(const float4*)(WO + (size_t)(kt * 64 + di) * DM + dt * 64 + c);
            *(float4*)&T[di][c] = v;
        }
        __syncthreads();
        ushort* dst = WObT + (size_t)(dt * 64 + di) * DM + kt * 64;
#pragma unroll
        for (int j = 0; j < 4; j++) {
            const int dc = cg * 16 + j * 4;
            usv4 o;
            o[0] = f2bf(T[dc + 0][di]); o[1] = f2bf(T[dc + 1][di]);
            o[2] = f2bf(T[dc + 2][di]); o[3] = f2bf(T[dc + 3][di]);
            *(usv4*)(dst + dc) = o;
        }
    }
}

// ---------------- Kernel A: QKV MFMA GEMM ----------------
__global__ __launch_bounds__(256) void qkv_mfma_k(
    const ushort* __restrict__ xb, const ushort* __restrict__ WbT,
    const float* __restrict__ bQ, const float* __restrict__ bK, const float* __restrict__ bV,
    ushort* __restrict__ Qb, ushort* __restrict__ Kb, ushort* __restrict__ Vtb)
{
    __shared__ ushort As[128 * 32];
    __shared__ ushort Bs[128 * 32];
    const int tid = threadIdx.x;
    const int w = tid >> 6, lane = tid & 63;
    const int l16 = lane & 15, quad = lane >> 4;
    const int jt = blockIdx.x;          // 0..17
    const int mt = blockIdx.y;          // 0..63
    const int t = jt / 6;
    const int jb = (jt % 6) * 128;
    const int mbase = mt * 128;

    const ushort* Bt = WbT + (size_t)t * (DM * DM) + (size_t)jb * DM;

    const int srow = (lane >> 2);
    const int scol = (lane & 3) * 8;
    const ushort* gA0 = xb + (size_t)(mbase + w * 32 + srow) * DM + scol;
    const ushort* gB0 = Bt + (size_t)(w * 32 + srow) * DM + scol;
    ushort* lA0 = As + (w * 32) * 32;
    ushort* lB0 = Bs + (w * 32) * 32;

    floatx4 acc[2][8];
#pragma unroll
    for (int m = 0; m < 2; m++)
#pragma unroll
        for (int n = 0; n < 8; n++) acc[m][n] = (floatx4){0.f, 0.f, 0.f, 0.f};

    for (int kt = 0; kt < 24; kt++) {
        const int k0 = kt * 32;
        __syncthreads();
        gld_lds16(gA0 + k0, lA0);
        gld_lds16(gA0 + (size_t)16 * DM + k0, lA0 + 16 * 32);
        gld_lds16(gB0 + k0, lB0);
        gld_lds16(gB0 + (size_t)16 * DM + k0, lB0 + 16 * 32);
        asm volatile("s_waitcnt vmcnt(0)" ::: "memory");
        __syncthreads();

        const ushort* Ab = As + (w * 32 + l16) * 32 + quad * 8;
        short8 a0 = *(const short8*)(Ab);
        short8 a1 = *(const short8*)(Ab + 16 * 32);
#pragma unroll
        for (int n = 0; n < 8; n++) {
            short8 b = *(const short8*)(Bs + (n * 16 + l16) * 32 + quad * 8);
            acc[0][n] = __builtin_amdgcn_mfma_f32_16x16x32_bf16(a0, b, acc[0][n], 0, 0, 0);
            acc[1][n] = __builtin_amdgcn_mfma_f32_16x16x32_bf16(a1, b, acc[1][n], 0, 0, 0);
        }
    }

    const float* bias = (t == 0) ? bQ : (t == 1) ? bK : bV;
#pragma unroll
    for (int m = 0; m < 2; m++) {
        const int mrow0 = mbase + w * 32 + m * 16 + quad * 4;
        const int bp = mrow0 >> 10;
        const int s0 = mrow0 & 1023;
#pragma unroll
        for (int n = 0; n < 8; n++) {
            const int col = jb + n * 16 + l16;
            const int head = col >> 6, h = col & 63;
            const size_t hb = ((size_t)bp * NH + head) * (SS * DH);
            const float bv = bias[head * DH + h];
            if (t == 0) {
#pragma unroll
                for (int r = 0; r < 4; r++)
                    Qb[hb + (size_t)(s0 + r) * DH + h] = f2bf((acc[m][n][r] + bv) * 0.125f);
            } else if (t == 1) {
#pragma unroll
                for (int r = 0; r < 4; r++)
                    Kb[hb + (size_t)(s0 + r) * DH + h] = f2bf(acc[m][n][r] + bv);
            } else {
                usv4 o;
#pragma unroll
                for (int r = 0; r < 4; r++) o[r] = f2bf(acc[m][n][r] + bv);
                *(usv4*)(Vtb + hb + (size_t)h * SS + s0) = o;
            }
        }
    }
}

// ---------------- Kernel B: MFMA flash attention (bf16 Z out) ----------------
__global__ __launch_bounds__(256) void attn_mfma_k(
    const ushort* __restrict__ Qb, const ushort* __restrict__ Kb,
    const ushort* __restrict__ Vtb, ushort* __restrict__ Zb)
{
    __shared__ __align__(16) ushort P_lds[4][16][72];
    const int head = blockIdx.x;
    const int wave = threadIdx.x >> 6;
    const int lane = threadIdx.x & 63;
    const int quad = lane >> 4;
    const int l16  = lane & 15;
    const int qbase = blockIdx.y * 64 + wave * 16;

    const size_t hb = (size_t)head * (SS * DH);
    const ushort* Qh = Qb + hb;
    const ushort* Kh = Kb + hb;
    const ushort* Vh = Vtb + hb;

    short8 a_q0 = *(const short8*)(Qh + (size_t)(qbase + l16) * DH + quad * 8);
    short8 a_q1 = *(const short8*)(Qh + (size_t)(qbase + l16) * DH + 32 + quad * 8);

    floatx4 o[4];
    float m_run[4], l_run[4];
#pragma unroll
    for (int r = 0; r < 4; r++) {
        o[r] = (floatx4){0.f, 0.f, 0.f, 0.f};
        m_run[r] = -1e30f; l_run[r] = 0.f;
    }

    const int kb_last = (qbase + 15) >> 6;
    for (int kb = 0; kb <= kb_last; kb++) {
        floatx4 c[4];
#pragma unroll
        for (int kg = 0; kg < 4; kg++) {
            const ushort* krow = Kh + (size_t)(kb * 64 + kg * 16 + l16) * DH + quad * 8;
            short8 b0 = *(const short8*)(krow);
            short8 b1 = *(const short8*)(krow + 32);
            floatx4 cc = (floatx4){0.f, 0.f, 0.f, 0.f};
            cc = __builtin_amdgcn_mfma_f32_16x16x32_bf16(a_q0, b0, cc, 0, 0, 0);
            cc = __builtin_amdgcn_mfma_f32_16x16x32_bf16(a_q1, b1, cc, 0, 0, 0);
            c[kg] = cc;
        }
        if (kb == kb_last) {
#pragma unroll
            for (int kg = 0; kg < 4; kg++) {
                const int key = kb * 64 + kg * 16 + l16;
#pragma unroll
                for (int r = 0; r < 4; r++) {
                    const int q = qbase + quad * 4 + r;
                    if (key > q) c[kg][r] = -1e30f;
                }
            }
        }
        float mt_[4];
#pragma unroll
        for (int r = 0; r < 4; r++) {
            float m0 = fmaxf(fmaxf(c[0][r], c[1][r]), fmaxf(c[2][r], c[3][r]));
            m0 = fmaxf(m0, __shfl_xor(m0, 1, 64));
            m0 = fmaxf(m0, __shfl_xor(m0, 2, 64));
            m0 = fmaxf(m0, __shfl_xor(m0, 4, 64));
            m0 = fmaxf(m0, __shfl_xor(m0, 8, 64));
            mt_[r] = m0;
        }
        float alpha[4], rs[4];
#pragma unroll
        for (int r = 0; r < 4; r++) {
            const float m_new = fmaxf(m_run[r], mt_[r]);
            alpha[r] = __expf(m_run[r] - m_new);
            m_run[r] = m_new;
            rs[r] = 0.f;
        }
#pragma unroll
        for (int kg = 0; kg < 4; kg++) {
#pragma unroll
            for (int r = 0; r < 4; r++) {
                const float p = __expf(c[kg][r] - m_run[r]);
                rs[r] += p;
                P_lds[wave][quad * 4 + r][kg * 16 + l16] = f2bf(p);
            }
        }
#pragma unroll
        for (int r = 0; r < 4; r++) {
            float s = rs[r];
            s += __shfl_xor(s, 1, 64);
            s += __shfl_xor(s, 2, 64);
            s += __shfl_xor(s, 4, 64);
            s += __shfl_xor(s, 8, 64);
            l_run[r] = l_run[r] * alpha[r] + s;
        }
#pragma unroll
        for (int hg = 0; hg < 4; hg++) {
#pragma unroll
            for (int r = 0; r < 4; r++) o[hg][r] *= alpha[r];
        }
        asm volatile("s_waitcnt lgkmcnt(0)" ::: "memory");
        short8 ap0 = *(const short8*)&P_lds[wave][l16][quad * 8];
        short8 ap1 = *(const short8*)&P_lds[wave][l16][32 + quad * 8];
#pragma unroll
        for (int hg = 0; hg < 4; hg++) {
            const ushort* vrow = Vh + (size_t)(hg * 16 + l16) * SS + kb * 64 + quad * 8;
            short8 bv0 = *(const short8*)(vrow);
            short8 bv1 = *(const short8*)(vrow + 32);
            o[hg] = __builtin_amdgcn_mfma_f32_16x16x32_bf16(ap0, bv0, o[hg], 0, 0, 0);
            o[hg] = __builtin_amdgcn_mfma_f32_16x16x32_bf16(ap1, bv1, o[hg], 0, 0, 0);
        }
        asm volatile("s_waitcnt lgkmcnt(0)" ::: "memory");
    }

    float inv[4];
#pragma unroll
    for (int r = 0; r < 4; r++) inv[r] = 1.f / l_run[r];
#pragma unroll
    for (int hg = 0; hg < 4; hg++) {
#pragma unroll
        for (int r = 0; r < 4; r++) {
            Zb[hb + (size_t)(qbase + quad * 4 + r) * DH + hg * 16 + l16] = f2bf(o[hg][r] * inv[r]);
        }
    }
}

// ---------------- Zd = Z(p=0) - Z(p=1) per head ----------------
__global__ __launch_bounds__(256) void zdiff_k(
    const ushort* __restrict__ Zb, ushort* __restrict__ Zd)
{
    const size_t e = ((size_t)blockIdx.x * 256 + threadIdx.x) * 8;
    const int bk = (int)(e >> 16);           // b*12+k
    const int off = (int)(e & 65535);
    const int b_ = bk / NH, k = bk % NH;
    const ushort* z0 = Zb + ((size_t)(b_ * 2) * NH + k) * (SS * DH) + off;
    const ushort* z1 = Zb + ((size_t)(b_ * 2 + 1) * NH + k) * (SS * DH) + off;
    short8 a = *(const short8*)z0;
    short8 c = *(const short8*)z1;
    short8 o;
#pragma unroll
    for (int i = 0; i < 8; i++)
        o[i] = (short)f2bf(bf2f((ushort)a[i]) - bf2f((ushort)c[i]));
    *(short8*)(Zd + e) = o;
}

// ---------------- Fused output projection: all 14 planes ----------------
// grid (6 nt, 16 mt, 4 b); 64-row x 128-col tiles; wave w owns rows mt*64+w*16..+15.
// Phase A: plane 0 = Zb[2b] @ WObT^T + bO
// Phase B: plane 1 = Zb[2b+1] @ WObT^T + bO  (kept in regs as s1)
// Phase C: plane 2+k = Zd[b,k] @ WO[k] + s1   (k = 0..11)
__global__ __launch_bounds__(256) void outproj_k(
    const ushort* __restrict__ Zb, const ushort* __restrict__ Zd,
    const ushort* __restrict__ WObT, const float* __restrict__ bO,
    float* __restrict__ out)
{
    __shared__ ushort As[64 * 32];
    __shared__ ushort Bs[128 * 32];
    const int tid = threadIdx.x;
    const int w = tid >> 6, lane = tid & 63;
    const int l16 = lane & 15, quad = lane >> 4;
    const int jb = blockIdx.x * 128;
    const int q0 = blockIdx.y * 64;
    const int b_ = blockIdx.z;

    // staging lane decomposition
    const int srow = lane >> 2;             // 0..15
    const int scol = (lane & 3) * 8;        // ushort offset within 32-k chunk
    const int arow = q0 + w * 16 + srow;    // global q row this lane stages
    const ushort* gB = WObT + (size_t)(jb + w * 32 + srow) * DM + scol;
    ushort* lA = As + (w * 16) * 32;
    ushort* lB0 = Bs + (w * 32) * 32;
    ushort* lB1 = Bs + (w * 32 + 16) * 32;

    const ushort* Afrag = As + (w * 16 + l16) * 32 + quad * 8;

    float bia[8];
#pragma unroll
    for (int n = 0; n < 8; n++) bia[n] = bO[jb + n * 16 + l16];

    floatx4 s1[8];
    // ---- Phases A & B: K=768 GEMM over Zb[2b+pp] ----
#pragma unroll 1
    for (int pp = 0; pp < 2; pp++) {
        const ushort* Zp = Zb + (size_t)(b_ * 2 + pp) * (NH * SS * DH);
        floatx4 acc[8];
#pragma unroll
        for (int n = 0; n < 8; n++) acc[n] = (floatx4){0.f, 0.f, 0.f, 0.f};
        for (int kt = 0; kt < 24; kt++) {
            const int k0 = kt * 32;
            __syncthreads();
            gld_lds16(Zp + (size_t)(k0 >> 6) * (SS * DH) + (size_t)arow * DH + (k0 & 63) + scol, lA);
            gld_lds16(gB + k0, lB0);
            gld_lds16(gB + (size_t)16 * DM + k0, lB1);
            asm volatile("s_waitcnt vmcnt(0)" ::: "memory");
            __syncthreads();
            short8 a = *(const short8*)(Afrag);
#pragma unroll
            for (int n = 0; n < 8; n++) {
                short8 b = *(const short8*)(Bs + (n * 16 + l16) * 32 + quad * 8);
                acc[n] = __builtin_amdgcn_mfma_f32_16x16x32_bf16(a, b, acc[n], 0, 0, 0);
            }
        }
        float* obase = out + ((size_t)(b_ * 14 + pp) * SS) * DM;
        const int qr = q0 + w * 16 + quad * 4;
#pragma unroll
        for (int n = 0; n < 8; n++) {
            const int d = jb + n * 16 + l16;
#pragma unroll
            for (int r = 0; r < 4; r++) {
                const float v = acc[n][r] + bia[n];
                obase[(size_t)(qr + r) * DM + d] = v;
                if (pp == 1) s1[n][r] = v;
            }
        }
    }

    // ---- Phase C: 12 per-head diff GEMMs, K=64 ----
    const ushort* Zdb = Zd + (size_t)b_ * (NH * SS * DH);
#pragma unroll 1
    for (int k = 0; k < NH; k++) {
        const ushort* Zdk = Zdb + (size_t)k * (SS * DH);
        floatx4 acc[8];
#pragma unroll
        for (int n = 0; n < 8; n++) acc[n] = (floatx4){0.f, 0.f, 0.f, 0.f};
#pragma unroll
        for (int kt = 0; kt < 2; kt++) {
            const int k0 = kt * 32;
            __syncthreads();
            gld_lds16(Zdk + (size_t)arow * DH + k0 + scol, lA);
            gld_lds16(gB + k * DH + k0, lB0);
            gld_lds16(gB + (size_t)16 * DM + k * DH + k0, lB1);
            asm volatile("s_waitcnt vmcnt(0)" ::: "memory");
            __syncthreads();
            short8 a = *(const short8*)(Afrag);
#pragma unroll
            for (int n = 0; n < 8; n++) {
                short8 b = *(const short8*)(Bs + (n * 16 + l16) * 32 + quad * 8);
                acc[n] = __builtin_amdgcn_mfma_f32_16x16x32_bf16(a, b, acc[n], 0, 0, 0);
            }
        }
        float* obase = out + ((size_t)(b_ * 14 + 2 + k) * SS) * DM;
        const int qr = q0 + w * 16 + quad * 4;
#pragma unroll
        for (int n = 0; n < 8; n++) {
            const int d = jb + n * 16 + l16;
#pragma unroll
            for (int r = 0; r < 4; r++)
                obase[(size_t)(qr + r) * DM + d] = acc[n][r] + s1[n][r];
        }
    }
}

extern "C" void kernel_launch(void* const* d_in, const int* in_sizes, int n_in,
                              void* d_out, int out_size, void* d_ws, size_t ws_size,
                              hipStream_t stream)
{
    const float* x0 = (const float*)d_in[0];
    const float* x1 = (const float*)d_in[1];
    const float* WQ = (const float*)d_in[2];
    const float* bQ = (const float*)d_in[3];
    const float* WK = (const float*)d_in[4];
    const float* bK = (const float*)d_in[5];
    const float* WV = (const float*)d_in[6];
    const float* bV = (const float*)d_in[7];
    const float* WO = (const float*)d_in[8];
    const float* bO = (const float*)d_in[9];
    float* out = (float*)d_out;

    ushort* ub   = (ushort*)d_ws;
    ushort* Qb   = ub;                        // 6291456
    ushort* Kb   = Qb + 6291456;
    ushort* Vtb  = Kb + 6291456;
    ushort* xb   = Vtb + 6291456;
    ushort* WbT  = xb + 6291456;              // 1769472
    ushort* Zb   = WbT + 1769472;             // 6291456
    ushort* WObT = Zb + 6291456;              // 589824
    ushort* Zd   = WObT + 589824;             // 3145728

    prep_k<<<dim3(3648), 256, 0, stream>>>(x0, x1, WQ, WK, WV, WO, xb, WbT, WObT);
    qkv_mfma_k<<<dim3(18, 64), 256, 0, stream>>>(xb, WbT, bQ, bK, bV, Qb, Kb, Vtb);
    attn_mfma_k<<<dim3(96, 16), 256, 0, stream>>>(Qb, Kb, Vtb, Zb);
    zdiff_k<<<dim3(1536), 256, 0, stream>>>(Zb, Zd);
    outproj_k<<<dim3(6, 16, 4), 256, 0, stream>>>(Zb, Zd, WObT, bO, out);
}